// Round 2
// baseline (354.973 us; speedup 1.0000x reference)
//
#include <hip/hip_runtime.h>
#include <math.h>

typedef __attribute__((ext_vector_type(8))) short bf16x8;
typedef __attribute__((ext_vector_type(4))) float f32x4;

// ================= compile-time Clebsch-Gordan tables =================
constexpr double cfact(int n){ double r=1.0; for(int i=2;i<=n;++i) r*=(double)i; return r; }
constexpr double csqrt_(double x){ double g=(x>1.0)?x:1.0; for(int i=0;i<100;++i) g=0.5*(g+x/g); return g; }
constexpr double cg_coef_(int l1,int m1,int l2,int m2,int l,int m){
  double pre = csqrt_((double)(2*l+1)*cfact(l1+l2-l)*cfact(l1-l2+l)*cfact(-l1+l2+l)/cfact(l1+l2+l+1));
  pre = pre*csqrt_(cfact(l+m)*cfact(l-m)*cfact(l1-m1)*cfact(l1+m1)*cfact(l2-m2)*cfact(l2+m2));
  double s=0.0;
  for(int k=0;k<=l1+l2-l;++k){
    int d0=k,d1=l1+l2-l-k,d2=l1-m1-k,d3=l2+m2-k,d4=l-l2+m1+k,d5=l-l1-m2+k;
    if(d0<0||d1<0||d2<0||d3<0||d4<0||d5<0) continue;
    double den=cfact(d0)*cfact(d1)*cfact(d2)*cfact(d3)*cfact(d4)*cfact(d5);
    s+=((k&1)?-1.0:1.0)/den;
  }
  return pre*s;
}
struct CGList{ int n; float coef[64]; int mi[64]; int ni[64]; int pi[64]; };
constexpr CGList build_cg(int l1,int l2,int l){
  CGList T{};
  for(int i=0;i<2*l1+1;++i){
    for(int j=0;j<2*l2+1;++j){
      int m1=i-l1, m2=j-l2, m=m1+m2;
      if(m<-l||m>l) continue;
      double c=cg_coef_(l1,m1,l2,m2,l,m);
      if(c>1e-12||c<-1e-12){
        T.coef[T.n]=(float)c; T.mi[T.n]=i; T.ni[T.n]=j; T.pi[T.n]=m+l; T.n++;
      }
    }
  }
  return T;
}

// ================= layout constants =================
__device__ __host__ constexpr int AOFF(int l){ return l==0?0: l==1?16: l==2?64:144; }
__device__ __host__ constexpr int MLs(int l){ return l==0?1024: l==1?1536: l==2?1792:1536; }
__device__ __host__ constexpr int WOFF(int l){ return l==0?0: l==1?16384: l==2?40960:69632; }
__device__ __host__ constexpr int SOFF(int l){ return l==0?0: l==1?1024: l==2?2560:4352; }
__device__ __host__ constexpr int ABASE(int l){ return l==0?0: l==1?65536: l==2?163840:278528; }

#define DEVFN __device__ __forceinline__
#define BP 68   // btile row pitch in words (272 B: 16B-aligned, stride-4 bank rotate)

DEVFN unsigned f2bf2(float x, float y){
  unsigned ux = __float_as_uint(x); ux = (ux + 0x7FFFu + ((ux>>16)&1u)) >> 16;
  unsigned uy = __float_as_uint(y); uy = (uy + 0x7FFFu + ((uy>>16)&1u)) >> 16;
  return (ux & 0xFFFFu) | (uy << 16);
}

template<int L1,int L2,int L>
DEVFN void cg_accum(const float2* F1, const float2* F2, float2* mid){
  constexpr CGList T = build_cg(L1,L2,L);
  #pragma unroll
  for(int e=0;e<T.n;++e){
    const float c = T.coef[e];
    const float2 a = F1[T.mi[e]];
    const float2 b = F2[T.ni[e]];
    float pr = a.x*b.x - a.y*b.y;
    float pim= a.x*b.y + a.y*b.x;
    mid[T.pi[e]].x += c*pr;
    mid[T.pi[e]].y += c*pim;
  }
}

// ===== K1: sum-of-squares; stages only the (l1,l2) activation segments =====
template<int L1,int L2,int L>
DEVFN void k1_body(const float* __restrict__ act, int b0, int ti,
                   float* __restrict__ sumsq, char* smem){
  constexpr int N1=2*L1+1, N2=2*L2+1, NP=2*L+1;
  constexpr int F4B = 8*N1 + ((L1==L2)?0:8*N2);   // float4 per batch staged
  constexpr int PIT = F4B + 1;                    // padded pitch (float4)
  constexpr int SH  = (L1==L2)?0:16*N1;           // F2 segment offset (float2)
  const int tid = threadIdx.x;
  float4* s4 = (float4*)smem;
  {
    const float4* actg = (const float4*)act + (size_t)b0*128;
    for(int i=tid; i<16*F4B; i+=256){
      int lb = i / F4B, e = i - lb*F4B;
      int so = (e < 8*N1) ? (AOFF(L1)/2 + e) : (AOFF(L2)/2 + (e - 8*N1));
      s4[lb*PIT + e] = actg[(size_t)lb*128 + so];
    }
  }
  __syncthreads();
  const int u = tid & 127, bh = tid >> 7;
  const int t = u>>3, s0 = (u&7)*2;
  float ssa=0.f, ssb=0.f;
  #pragma unroll 2
  for(int bi=0;bi<8;++bi){
    const int lb = bh*8 + bi;
    const float2* arow = (const float2*)(s4 + lb*PIT);
    float2 F1[N1], F2a[N2], F2b[N2], mida[NP], midb[NP];
    #pragma unroll
    for(int m=0;m<N1;++m) F1[m]=arow[t*N1+m];
    #pragma unroll
    for(int n=0;n<N2;++n){
      F2a[n]=arow[SH + s0*N2+n];
      F2b[n]=arow[SH + (s0+1)*N2+n];
    }
    #pragma unroll
    for(int p=0;p<NP;++p){ mida[p]=make_float2(0.f,0.f); midb[p]=make_float2(0.f,0.f); }
    cg_accum<L1,L2,L>(F1,F2a,mida);
    cg_accum<L1,L2,L>(F1,F2b,midb);
    #pragma unroll
    for(int p=0;p<NP;++p){
      ssa += mida[p].x*mida[p].x + mida[p].y*mida[p].y;
      ssb += midb[p].x*midb[p].x + midb[p].y*midb[p].y;
    }
  }
  atomicAdd(&sumsq[ti*256 + 2*u],     ssa);
  atomicAdd(&sumsq[ti*256 + 2*u + 1], ssb);
}

__global__ __launch_bounds__(256,6) void k_sumsq(const float* __restrict__ act,
                                                 float* __restrict__ sumsq){
  __shared__ __align__(16) char smem[24832];   // max triple (3,2): 16*97*16
  int bid=blockIdx.x;                          // 23 triples * 128 chunks
  const int order[23] = {22,16,21,18,15,20,13,9,14,8,17,7,12,6,10,3,5,19,2,11,1,4,0};
  int ti = order[bid>>7];
  int b0 = (bid&127)*16;
  switch(ti){
    case 0:  k1_body<0,0,0>(act,b0,ti,sumsq,smem); break;
    case 1:  k1_body<1,1,0>(act,b0,ti,sumsq,smem); break;
    case 2:  k1_body<2,2,0>(act,b0,ti,sumsq,smem); break;
    case 3:  k1_body<3,3,0>(act,b0,ti,sumsq,smem); break;
    case 4:  k1_body<1,0,1>(act,b0,ti,sumsq,smem); break;
    case 5:  k1_body<1,1,1>(act,b0,ti,sumsq,smem); break;
    case 6:  k1_body<2,1,1>(act,b0,ti,sumsq,smem); break;
    case 7:  k1_body<2,2,1>(act,b0,ti,sumsq,smem); break;
    case 8:  k1_body<3,2,1>(act,b0,ti,sumsq,smem); break;
    case 9:  k1_body<3,3,1>(act,b0,ti,sumsq,smem); break;
    case 10: k1_body<1,1,2>(act,b0,ti,sumsq,smem); break;
    case 11: k1_body<2,0,2>(act,b0,ti,sumsq,smem); break;
    case 12: k1_body<2,1,2>(act,b0,ti,sumsq,smem); break;
    case 13: k1_body<2,2,2>(act,b0,ti,sumsq,smem); break;
    case 14: k1_body<3,1,2>(act,b0,ti,sumsq,smem); break;
    case 15: k1_body<3,2,2>(act,b0,ti,sumsq,smem); break;
    case 16: k1_body<3,3,2>(act,b0,ti,sumsq,smem); break;
    case 17: k1_body<2,1,3>(act,b0,ti,sumsq,smem); break;
    case 18: k1_body<2,2,3>(act,b0,ti,sumsq,smem); break;
    case 19: k1_body<3,0,3>(act,b0,ti,sumsq,smem); break;
    case 20: k1_body<3,1,3>(act,b0,ti,sumsq,smem); break;
    case 21: k1_body<3,2,3>(act,b0,ti,sumsq,smem); break;
    default: k1_body<3,3,3>(act,b0,ti,sumsq,smem); break;
  }
}

// ============ K2: scale + build bf16 A matrices (scale folded into W) =======
__global__ __launch_bounds__(256) void k_buildA(const float* __restrict__ W,
                                                const float* __restrict__ bn,
                                                const float* __restrict__ sumsq,
                                                short* __restrict__ A){
  int idx = blockIdx.x*256 + threadIdx.x;   // 5888 channels
  if(idx>=5888) return;
  int l = (idx<1024)?0 : (idx<2560)?1 : (idx<4352)?2 : 3;
  float divi = (l==0)?(1.f/2048.f) : (l==1)?(1.f/6144.f) : (l==2)?(1.f/10240.f) : (1.f/14336.f);
  float bstd = sqrtf(sumsq[idx]*divi);
  float nstd = 0.5f*(bn[idx]+bstd);
  float s = 1.f/(nstd+1e-5f);
  int c = idx - SOFF(l);
  int Ml = MLs(l);
  const float2* wbase = (const float2*)W + WOFF(l) + c;
  unsigned* Aw = (unsigned*)(A + ABASE(l));   // row pitch = Ml words (2*Ml bf16)
  for(int o=0;o<16;++o){
    float2 w = wbase[(size_t)o*Ml];
    Aw[(size_t)o*Ml + c]      = f2bf2(w.x*s, -w.y*s);
    Aw[(size_t)(o+16)*Ml + c] = f2bf2(w.y*s,  w.x*s);
  }
}

// ======== K3: fused recompute-GEMM, one l per kernel ========
// Block = B batches of one l; K-loop over ALL triples of l (4 chunks of
// 64 words each). Per chunk: phase1 (256 thr recompute CG mid -> LDS
// btile, exactly 1-2 pair-units/thread), A-fragment prefetch to regs,
// barrier, MFMA accumulate (full-K register accumulation -> single
// float2 store per output element at the end; no atomics, no out memset).

// ---- prologue: stage act rows (pitch 257 float2) + zero btile ----
template<int B,int NTIL>
DEVFN void kf_pre(const float* __restrict__ act, char* smem, int b0){
  const int tid = threadIdx.x;
  const float2* actg2 = (const float2*)act + (size_t)b0*256;
  float2* sa = (float2*)smem;
  for(int i=tid; i<B*256; i+=256){
    int lb = i>>8, e = i&255;
    sa[lb*257 + e] = actg2[(size_t)lb*256 + e];
  }
  unsigned* btile = (unsigned*)(smem + B*2056);
  for(int i=tid; i<NTIL*16*BP; i+=256) btile[i]=0;
  __syncthreads();
}

template<int L1,int L2,int L,int Q,int B,int NTIL>
DEVFN void kf_triple(const float2* __restrict__ sa, unsigned* __restrict__ btile,
                     const unsigned* __restrict__ Aw, f32x4& cR, f32x4& cI){
  constexpr int N1=2*L1+1, N2=2*L2+1, NP=2*L+1;
  constexpr int Ml = MLs(L);
  constexpr int R = (B+7)/8;
  const int tid = threadIdx.x;
  const int lane = tid & 63, w = tid >> 6;
  const int col = lane & 15, quad = lane >> 4;
  const int up = tid & 31, bi = tid >> 5;
  #pragma unroll
  for(int cc=0; cc<4; ++cc){
    // ---- phase1: CG recompute for 64 K-words x B batches -> btile ----
    {
      const int u = cc*32 + up;              // channel pair (2u,2u+1)
      const int t = u>>3, s0 = (u&7)*2;
      #pragma unroll
      for(int r=0; r<R; ++r){
        const int lb = bi + r*8;             // B in {8,16}: always < B
        const float2* arow = sa + lb*257;
        float2 F1[N1], F2a[N2], F2b[N2], mida[NP], midb[NP];
        #pragma unroll
        for(int m=0;m<N1;++m) F1[m]=arow[AOFF(L1)+t*N1+m];
        #pragma unroll
        for(int n=0;n<N2;++n){
          F2a[n]=arow[AOFF(L2)+s0*N2+n];
          F2b[n]=arow[AOFF(L2)+(s0+1)*N2+n];
        }
        #pragma unroll
        for(int p=0;p<NP;++p){ mida[p]=make_float2(0.f,0.f); midb[p]=make_float2(0.f,0.f); }
        cg_accum<L1,L2,L>(F1,F2a,mida);
        cg_accum<L1,L2,L>(F1,F2b,midb);
        #pragma unroll
        for(int p=0;p<NP;++p){
          uint2 v; v.x = f2bf2(mida[p].x, mida[p].y); v.y = f2bf2(midb[p].x, midb[p].y);
          *(uint2*)(btile + (size_t)(lb*NP+p)*BP + 2*up) = v;
        }
      }
    }
    // ---- A-fragment prefetch (completes during barrier wait) ----
    uint4 pa0[4], pa1[4];
    if(w < NTIL){
      const unsigned* Ab = Aw + (Q*4+cc)*64 + quad*4;
      #pragma unroll
      for(int ks=0; ks<4; ++ks){
        pa0[ks] = *(const uint4*)(Ab + (size_t)col*Ml + ks*16);
        pa1[ks] = *(const uint4*)(Ab + (size_t)(col+16)*Ml + ks*16);
      }
    }
    __syncthreads();
    // ---- MFMA accumulate ----
    if(w < NTIL){
      const unsigned* bb = btile + (w*16+col)*BP + quad*4;
      #pragma unroll
      for(int ks=0; ks<4; ++ks){
        bf16x8 b  = *(const bf16x8*)(bb + ks*16);
        bf16x8 A0 = *(const bf16x8*)&pa0[ks];
        bf16x8 A1 = *(const bf16x8*)&pa1[ks];
        cR = __builtin_amdgcn_mfma_f32_16x16x32_bf16(A0, b, cR, 0, 0, 0);
        cI = __builtin_amdgcn_mfma_f32_16x16x32_bf16(A1, b, cI, 0, 0, 0);
      }
    }
    __syncthreads();
  }
}

template<int L,int B,int NTIL>
DEVFN void kf_epi(float* __restrict__ out, int b0, f32x4 cR, f32x4 cI){
  constexpr int NP = 2*L+1;
  const int tid = threadIdx.x, lane = tid & 63, w = tid >> 6;
  const int col = lane & 15, quad = lane >> 4;
  if(w < NTIL){
    const int r = w*16 + col;
    if(r < B*NP){
      const int b = b0 + r/NP, p = r - (r/NP)*NP;
      float2* o2 = (float2*)out + (size_t)b*256 + AOFF(L);
      #pragma unroll
      for(int i=0;i<4;++i) o2[(quad*4+i)*NP + p] = make_float2(cR[i], cI[i]);
    }
  }
}

__global__ __launch_bounds__(256,4) void k_fused0(const float* __restrict__ act,
    const short* __restrict__ A, float* __restrict__ out){
  __shared__ __align__(16) char smem[16*2056 + 16*BP*4];     // 37248
  const int b0 = blockIdx.x*16;
  kf_pre<16,1>(act,smem,b0);
  const float2* sa=(const float2*)smem;
  unsigned* btile=(unsigned*)(smem+16*2056);
  const unsigned* Aw=(const unsigned*)(A+ABASE(0));
  f32x4 cR={0.f,0.f,0.f,0.f}, cI={0.f,0.f,0.f,0.f};
  kf_triple<0,0,0,0,16,1>(sa,btile,Aw,cR,cI);
  kf_triple<1,1,0,1,16,1>(sa,btile,Aw,cR,cI);
  kf_triple<2,2,0,2,16,1>(sa,btile,Aw,cR,cI);
  kf_triple<3,3,0,3,16,1>(sa,btile,Aw,cR,cI);
  kf_epi<0,16,1>(out,b0,cR,cI);
}

__global__ __launch_bounds__(256,4) void k_fused1(const float* __restrict__ act,
    const short* __restrict__ A, float* __restrict__ out){
  __shared__ __align__(16) char smem[16*2056 + 48*BP*4];     // 45952
  const int b0 = blockIdx.x*16;
  kf_pre<16,3>(act,smem,b0);
  const float2* sa=(const float2*)smem;
  unsigned* btile=(unsigned*)(smem+16*2056);
  const unsigned* Aw=(const unsigned*)(A+ABASE(1));
  f32x4 cR={0.f,0.f,0.f,0.f}, cI={0.f,0.f,0.f,0.f};
  kf_triple<1,0,1,0,16,3>(sa,btile,Aw,cR,cI);
  kf_triple<1,1,1,1,16,3>(sa,btile,Aw,cR,cI);
  kf_triple<2,1,1,2,16,3>(sa,btile,Aw,cR,cI);
  kf_triple<2,2,1,3,16,3>(sa,btile,Aw,cR,cI);
  kf_triple<3,2,1,4,16,3>(sa,btile,Aw,cR,cI);
  kf_triple<3,3,1,5,16,3>(sa,btile,Aw,cR,cI);
  kf_epi<1,16,3>(out,b0,cR,cI);
}

__global__ __launch_bounds__(256,4) void k_fused2(const float* __restrict__ act,
    const short* __restrict__ A, float* __restrict__ out){
  __shared__ __align__(16) char smem[8*2056 + 48*BP*4];      // 29504
  const int b0 = blockIdx.x*8;
  kf_pre<8,3>(act,smem,b0);
  const float2* sa=(const float2*)smem;
  unsigned* btile=(unsigned*)(smem+8*2056);
  const unsigned* Aw=(const unsigned*)(A+ABASE(2));
  f32x4 cR={0.f,0.f,0.f,0.f}, cI={0.f,0.f,0.f,0.f};
  kf_triple<1,1,2,0,8,3>(sa,btile,Aw,cR,cI);
  kf_triple<2,0,2,1,8,3>(sa,btile,Aw,cR,cI);
  kf_triple<2,1,2,2,8,3>(sa,btile,Aw,cR,cI);
  kf_triple<2,2,2,3,8,3>(sa,btile,Aw,cR,cI);
  kf_triple<3,1,2,4,8,3>(sa,btile,Aw,cR,cI);
  kf_triple<3,2,2,5,8,3>(sa,btile,Aw,cR,cI);
  kf_triple<3,3,2,6,8,3>(sa,btile,Aw,cR,cI);
  kf_epi<2,8,3>(out,b0,cR,cI);
}

__global__ __launch_bounds__(256,4) void k_fused3(const float* __restrict__ act,
    const short* __restrict__ A, float* __restrict__ out){
  __shared__ __align__(16) char smem[8*2056 + 64*BP*4];      // 33856
  const int b0 = blockIdx.x*8;
  kf_pre<8,4>(act,smem,b0);
  const float2* sa=(const float2*)smem;
  unsigned* btile=(unsigned*)(smem+8*2056);
  const unsigned* Aw=(const unsigned*)(A+ABASE(3));
  f32x4 cR={0.f,0.f,0.f,0.f}, cI={0.f,0.f,0.f,0.f};
  kf_triple<2,1,3,0,8,4>(sa,btile,Aw,cR,cI);
  kf_triple<2,2,3,1,8,4>(sa,btile,Aw,cR,cI);
  kf_triple<3,0,3,2,8,4>(sa,btile,Aw,cR,cI);
  kf_triple<3,1,3,3,8,4>(sa,btile,Aw,cR,cI);
  kf_triple<3,2,3,4,8,4>(sa,btile,Aw,cR,cI);
  kf_triple<3,3,3,5,8,4>(sa,btile,Aw,cR,cI);
  kf_epi<3,8,4>(out,b0,cR,cI);
}

// ================= host launch =================
extern "C" void kernel_launch(void* const* d_in, const int* in_sizes, int n_in,
                              void* d_out, int out_size, void* d_ws, size_t ws_size,
                              hipStream_t stream) {
  const float* act = (const float*)d_in[0];   // (2048,256,2) f32
  const float* W   = (const float*)d_in[1];   // (94208,2) f32
  const float* bn  = (const float*)d_in[2];   // (5888,) f32
  float* out = (float*)d_out;                 // (2048,256,2) f32

  float* sumsq = (float*)d_ws;                          // 5888 f32
  short* A     = (short*)((char*)d_ws + 24576);         // 376832 bf16 (754 KB)

  hipMemsetAsync(sumsq, 0, 5888*sizeof(float), stream);
  hipLaunchKernelGGL(k_sumsq,  dim3(23*128), dim3(256), 0, stream, act, sumsq);
  hipLaunchKernelGGL(k_buildA, dim3(23),     dim3(256), 0, stream, W, bn, sumsq, A);
  hipLaunchKernelGGL(k_fused0, dim3(128),    dim3(256), 0, stream, act, A, out);
  hipLaunchKernelGGL(k_fused1, dim3(128),    dim3(256), 0, stream, act, A, out);
  hipLaunchKernelGGL(k_fused2, dim3(256),    dim3(256), 0, stream, act, A, out);
  hipLaunchKernelGGL(k_fused3, dim3(256),    dim3(256), 0, stream, act, A, out);
}

// Round 3
// 225.818 us; speedup vs baseline: 1.5719x; 1.5719x over previous
//
#include <hip/hip_runtime.h>
#include <math.h>

typedef __attribute__((ext_vector_type(8))) short bf16x8;
typedef __attribute__((ext_vector_type(4))) float f32x4;

// ================= compile-time Clebsch-Gordan tables =================
constexpr double cfact(int n){ double r=1.0; for(int i=2;i<=n;++i) r*=(double)i; return r; }
constexpr double csqrt_(double x){ double g=(x>1.0)?x:1.0; for(int i=0;i<100;++i) g=0.5*(g+x/g); return g; }
constexpr double cg_coef_(int l1,int m1,int l2,int m2,int l,int m){
  double pre = csqrt_((double)(2*l+1)*cfact(l1+l2-l)*cfact(l1-l2+l)*cfact(-l1+l2+l)/cfact(l1+l2+l+1));
  pre = pre*csqrt_(cfact(l+m)*cfact(l-m)*cfact(l1-m1)*cfact(l1+m1)*cfact(l2-m2)*cfact(l2+m2));
  double s=0.0;
  for(int k=0;k<=l1+l2-l;++k){
    int d0=k,d1=l1+l2-l-k,d2=l1-m1-k,d3=l2+m2-k,d4=l-l2+m1+k,d5=l-l1-m2+k;
    if(d0<0||d1<0||d2<0||d3<0||d4<0||d5<0) continue;
    double den=cfact(d0)*cfact(d1)*cfact(d2)*cfact(d3)*cfact(d4)*cfact(d5);
    s+=((k&1)?-1.0:1.0)/den;
  }
  return pre*s;
}
struct CGList{ int n; float coef[64]; int mi[64]; int ni[64]; int pi[64]; };
constexpr CGList build_cg(int l1,int l2,int l){
  CGList T{};
  for(int i=0;i<2*l1+1;++i){
    for(int j=0;j<2*l2+1;++j){
      int m1=i-l1, m2=j-l2, m=m1+m2;
      if(m<-l||m>l) continue;
      double c=cg_coef_(l1,m1,l2,m2,l,m);
      if(c>1e-12||c<-1e-12){
        T.coef[T.n]=(float)c; T.mi[T.n]=i; T.ni[T.n]=j; T.pi[T.n]=m+l; T.n++;
      }
    }
  }
  return T;
}

// ================= layout constants =================
__device__ __host__ constexpr int AOFF(int l){ return l==0?0: l==1?16: l==2?64:144; }
__device__ __host__ constexpr int MLs(int l){ return l==0?1024: l==1?1536: l==2?1792:1536; }
__device__ __host__ constexpr int WOFF(int l){ return l==0?0: l==1?16384: l==2?40960:69632; }
__device__ __host__ constexpr int SOFF(int l){ return l==0?0: l==1?1024: l==2?2560:4352; }
__device__ __host__ constexpr int ABASE(int l){ return l==0?0: l==1?65536: l==2?163840:278528; }

#define DEVFN __device__ __forceinline__
#define BP 68   // btile row pitch in words (272 B, 16B-aligned)

DEVFN unsigned f2bf2(float x, float y){
  unsigned ux = __float_as_uint(x); ux = (ux + 0x7FFFu + ((ux>>16)&1u)) >> 16;
  unsigned uy = __float_as_uint(y); uy = (uy + 0x7FFFu + ((uy>>16)&1u)) >> 16;
  return (ux & 0xFFFFu) | (uy << 16);
}

template<int L1,int L2,int L>
DEVFN void cg_accum(const float2* F1, const float2* F2, float2* mid){
  constexpr CGList T = build_cg(L1,L2,L);
  #pragma unroll
  for(int e=0;e<T.n;++e){
    const float c = T.coef[e];
    const float2 a = F1[T.mi[e]];
    const float2 b = F2[T.ni[e]];
    float pr = a.x*b.x - a.y*b.y;
    float pim= a.x*b.y + a.y*b.x;
    mid[T.pi[e]].x += c*pr;
    mid[T.pi[e]].y += c*pim;
  }
}

// ===== K1: sum-of-squares (round-0 structure, mid-store removed) =====
template<int L1,int L2,int L>
DEVFN void k1_body(const float2* __restrict__ acts, int u, int bh,
                   float& ssa, float& ssb){
  constexpr int N1=2*L1+1, N2=2*L2+1, NP=2*L+1;
  const int t = u>>3, s0 = (u&7)*2;
  #pragma unroll 2
  for(int bi=0;bi<8;++bi){
    const int row = bh*8 + bi;
    const float2* arow = acts + row*256;
    float2 F1[N1], F2a[N2], F2b[N2], mida[NP], midb[NP];
    #pragma unroll
    for(int m=0;m<N1;++m) F1[m]=arow[AOFF(L1)+t*N1+m];
    #pragma unroll
    for(int n=0;n<N2;++n){
      F2a[n]=arow[AOFF(L2)+s0*N2+n];
      F2b[n]=arow[AOFF(L2)+(s0+1)*N2+n];
    }
    #pragma unroll
    for(int p=0;p<NP;++p){ mida[p]=make_float2(0.f,0.f); midb[p]=make_float2(0.f,0.f); }
    cg_accum<L1,L2,L>(F1,F2a,mida);
    cg_accum<L1,L2,L>(F1,F2b,midb);
    #pragma unroll
    for(int p=0;p<NP;++p){
      ssa += mida[p].x*mida[p].x + mida[p].y*mida[p].y;
      ssb += midb[p].x*midb[p].x + midb[p].y*midb[p].y;
    }
  }
}

__global__ __launch_bounds__(256) void k_sumsq(const float* __restrict__ act,
                                               float* __restrict__ sumsq){
  __shared__ float2 acts[16*256];            // 32 KB: 16 act rows
  int bid=blockIdx.x;                        // 23 triples * 128 chunks
  const int order[23] = {22,16,21,18,15,20,13,9,14,8,17,7,12,6,10,3,5,19,2,11,1,4,0};
  int ti = order[bid>>7];
  int b0 = (bid&127)*16;
  const int tid = threadIdx.x;
  {
    const float4* ag = (const float4*)act + (size_t)b0*128;
    float4* as4 = (float4*)acts;
    #pragma unroll
    for(int j=0;j<8;++j) as4[j*256+tid] = ag[j*256+tid];
  }
  __syncthreads();
  const int u = tid & 127, bh = tid >> 7;    // channels (2u,2u+1), b-half bh
  float ssa=0.f, ssb=0.f;
  switch(ti){
    case 0:  k1_body<0,0,0>(acts,u,bh,ssa,ssb); break;
    case 1:  k1_body<1,1,0>(acts,u,bh,ssa,ssb); break;
    case 2:  k1_body<2,2,0>(acts,u,bh,ssa,ssb); break;
    case 3:  k1_body<3,3,0>(acts,u,bh,ssa,ssb); break;
    case 4:  k1_body<1,0,1>(acts,u,bh,ssa,ssb); break;
    case 5:  k1_body<1,1,1>(acts,u,bh,ssa,ssb); break;
    case 6:  k1_body<2,1,1>(acts,u,bh,ssa,ssb); break;
    case 7:  k1_body<2,2,1>(acts,u,bh,ssa,ssb); break;
    case 8:  k1_body<3,2,1>(acts,u,bh,ssa,ssb); break;
    case 9:  k1_body<3,3,1>(acts,u,bh,ssa,ssb); break;
    case 10: k1_body<1,1,2>(acts,u,bh,ssa,ssb); break;
    case 11: k1_body<2,0,2>(acts,u,bh,ssa,ssb); break;
    case 12: k1_body<2,1,2>(acts,u,bh,ssa,ssb); break;
    case 13: k1_body<2,2,2>(acts,u,bh,ssa,ssb); break;
    case 14: k1_body<3,1,2>(acts,u,bh,ssa,ssb); break;
    case 15: k1_body<3,2,2>(acts,u,bh,ssa,ssb); break;
    case 16: k1_body<3,3,2>(acts,u,bh,ssa,ssb); break;
    case 17: k1_body<2,1,3>(acts,u,bh,ssa,ssb); break;
    case 18: k1_body<2,2,3>(acts,u,bh,ssa,ssb); break;
    case 19: k1_body<3,0,3>(acts,u,bh,ssa,ssb); break;
    case 20: k1_body<3,1,3>(acts,u,bh,ssa,ssb); break;
    case 21: k1_body<3,2,3>(acts,u,bh,ssa,ssb); break;
    default: k1_body<3,3,3>(acts,u,bh,ssa,ssb); break;
  }
  atomicAdd(&sumsq[ti*256 + 2*u],     ssa);
  atomicAdd(&sumsq[ti*256 + 2*u + 1], ssb);
}

// ============ K2: scale + build bf16 A matrices (scale folded into W) =======
__global__ __launch_bounds__(256) void k_buildA(const float* __restrict__ W,
                                                const float* __restrict__ bn,
                                                const float* __restrict__ sumsq,
                                                short* __restrict__ A){
  int idx = blockIdx.x*256 + threadIdx.x;   // 5888 channels
  if(idx>=5888) return;
  int l = (idx<1024)?0 : (idx<2560)?1 : (idx<4352)?2 : 3;
  float divi = (l==0)?(1.f/2048.f) : (l==1)?(1.f/6144.f) : (l==2)?(1.f/10240.f) : (1.f/14336.f);
  float bstd = sqrtf(sumsq[idx]*divi);
  float nstd = 0.5f*(bn[idx]+bstd);
  float s = 1.f/(nstd+1e-5f);
  int c = idx - SOFF(l);
  int Ml = MLs(l);
  const float2* wbase = (const float2*)W + WOFF(l) + c;
  unsigned* Aw = (unsigned*)(A + ABASE(l));   // row pitch = Ml words (2*Ml bf16)
  for(int o=0;o<16;++o){
    float2 w = wbase[(size_t)o*Ml];
    Aw[(size_t)o*Ml + c]      = f2bf2(w.x*s, -w.y*s);
    Aw[(size_t)(o+16)*Ml + c] = f2bf2(w.y*s,  w.x*s);
  }
}

// ======== K3: fused recompute-GEMM, MERGED (all l in one launch) ========
// Block = 8 batches of one l; K-loop over all triples of l (4 chunks of
// 64 words each). Full-K register accumulation -> one float2 store per
// output element (no atomics, no out memset). Grid = 1024 blocks, LDS
// 33.9 KB -> 4 blocks/CU co-resident so barriers overlap across blocks.

// ---- prologue: stage 8 act rows (pitch 257 float2) + zero btile ----
template<int NTIL>
DEVFN void kf_pre(const float* __restrict__ act, char* smem, int b0){
  const int tid = threadIdx.x;
  const float2* actg2 = (const float2*)act + (size_t)b0*256;
  float2* sa = (float2*)smem;
  for(int i=tid; i<8*256; i+=256){
    int lb = i>>8, e = i&255;
    sa[lb*257 + e] = actg2[(size_t)lb*256 + e];
  }
  unsigned* btile = (unsigned*)(smem + 8*2056);
  for(int i=tid; i<NTIL*16*BP; i+=256) btile[i]=0;
  __syncthreads();
}

template<int L1,int L2,int L,int Q,int NTIL>
DEVFN void kf_triple(const float2* __restrict__ sa, unsigned* __restrict__ btile,
                     const unsigned* __restrict__ Aw, f32x4& cR, f32x4& cI){
  constexpr int N1=2*L1+1, N2=2*L2+1, NP=2*L+1;
  constexpr int Ml = MLs(L);
  const int tid = threadIdx.x;
  const int lane = tid & 63, w = tid >> 6;
  const int col = lane & 15, quad = lane >> 4;
  const int up = tid & 31, bi = tid >> 5;    // channel-pair-in-chunk, batch
  #pragma unroll
  for(int cc=0; cc<4; ++cc){
    // ---- phase1: CG recompute for 64 K-words x 8 batches -> btile ----
    {
      const int u = cc*32 + up;              // channel pair (2u,2u+1)
      const int t = u>>3, s0 = (u&7)*2;
      const float2* arow = sa + bi*257;
      float2 F1[N1], F2a[N2], F2b[N2], mida[NP], midb[NP];
      #pragma unroll
      for(int m=0;m<N1;++m) F1[m]=arow[AOFF(L1)+t*N1+m];
      #pragma unroll
      for(int n=0;n<N2;++n){
        F2a[n]=arow[AOFF(L2)+s0*N2+n];
        F2b[n]=arow[AOFF(L2)+(s0+1)*N2+n];
      }
      #pragma unroll
      for(int p=0;p<NP;++p){ mida[p]=make_float2(0.f,0.f); midb[p]=make_float2(0.f,0.f); }
      cg_accum<L1,L2,L>(F1,F2a,mida);
      cg_accum<L1,L2,L>(F1,F2b,midb);
      #pragma unroll
      for(int p=0;p<NP;++p){
        uint2 v; v.x = f2bf2(mida[p].x, mida[p].y); v.y = f2bf2(midb[p].x, midb[p].y);
        *(uint2*)(btile + (size_t)(bi*NP+p)*BP + 2*up) = v;
      }
    }
    // ---- A-fragment prefetch (completes during barrier wait) ----
    uint4 pa0[4], pa1[4];
    if(w < NTIL){
      const unsigned* Ab = Aw + (Q*4+cc)*64 + quad*4;
      #pragma unroll
      for(int ks=0; ks<4; ++ks){
        pa0[ks] = *(const uint4*)(Ab + (size_t)col*Ml + ks*16);
        pa1[ks] = *(const uint4*)(Ab + (size_t)(col+16)*Ml + ks*16);
      }
    }
    __syncthreads();
    // ---- MFMA accumulate ----
    if(w < NTIL){
      const unsigned* bb = btile + (w*16+col)*BP + quad*4;
      #pragma unroll
      for(int ks=0; ks<4; ++ks){
        bf16x8 b  = *(const bf16x8*)(bb + ks*16);
        bf16x8 A0 = *(const bf16x8*)&pa0[ks];
        bf16x8 A1 = *(const bf16x8*)&pa1[ks];
        cR = __builtin_amdgcn_mfma_f32_16x16x32_bf16(A0, b, cR, 0, 0, 0);
        cI = __builtin_amdgcn_mfma_f32_16x16x32_bf16(A1, b, cI, 0, 0, 0);
      }
    }
    __syncthreads();
  }
}

template<int L,int NTIL>
DEVFN void kf_epi(float* __restrict__ out, int b0, f32x4 cR, f32x4 cI){
  constexpr int NP = 2*L+1;
  const int tid = threadIdx.x, lane = tid & 63, w = tid >> 6;
  const int col = lane & 15, quad = lane >> 4;
  if(w < NTIL){
    const int r = w*16 + col;
    if(r < 8*NP){
      const int b = b0 + r/NP, p = r - (r/NP)*NP;
      float2* o2 = (float2*)out + (size_t)b*256 + AOFF(L);
      #pragma unroll
      for(int i=0;i<4;++i) o2[(quad*4+i)*NP + p] = make_float2(cR[i], cI[i]);
    }
  }
}

__global__ __launch_bounds__(256,4) void k_fusedall(const float* __restrict__ act,
    const short* __restrict__ A, float* __restrict__ out){
  __shared__ __align__(16) char smem[8*2056 + 64*BP*4];   // 33856 B
  const int bid = blockIdx.x;                             // 1024
  float2* sa_ = (float2*)smem;
  unsigned* bt = (unsigned*)(smem + 8*2056);
  f32x4 cR={0.f,0.f,0.f,0.f}, cI={0.f,0.f,0.f,0.f};
  if(bid < 256){                                          // l=3, rows 56, NTIL 4
    const int b0 = bid*8;
    kf_pre<4>(act,smem,b0);
    const unsigned* Aw=(const unsigned*)(A+ABASE(3));
    kf_triple<2,1,3,0,4>(sa_,bt,Aw,cR,cI);
    kf_triple<2,2,3,1,4>(sa_,bt,Aw,cR,cI);
    kf_triple<3,0,3,2,4>(sa_,bt,Aw,cR,cI);
    kf_triple<3,1,3,3,4>(sa_,bt,Aw,cR,cI);
    kf_triple<3,2,3,4,4>(sa_,bt,Aw,cR,cI);
    kf_triple<3,3,3,5,4>(sa_,bt,Aw,cR,cI);
    kf_epi<3,4>(out,b0,cR,cI);
  } else if(bid < 512){                                   // l=2, rows 40, NTIL 3
    const int b0 = (bid-256)*8;
    kf_pre<3>(act,smem,b0);
    const unsigned* Aw=(const unsigned*)(A+ABASE(2));
    kf_triple<1,1,2,0,3>(sa_,bt,Aw,cR,cI);
    kf_triple<2,0,2,1,3>(sa_,bt,Aw,cR,cI);
    kf_triple<2,1,2,2,3>(sa_,bt,Aw,cR,cI);
    kf_triple<2,2,2,3,3>(sa_,bt,Aw,cR,cI);
    kf_triple<3,1,2,4,3>(sa_,bt,Aw,cR,cI);
    kf_triple<3,2,2,5,3>(sa_,bt,Aw,cR,cI);
    kf_triple<3,3,2,6,3>(sa_,bt,Aw,cR,cI);
    kf_epi<2,3>(out,b0,cR,cI);
  } else if(bid < 768){                                   // l=1, rows 24, NTIL 2
    const int b0 = (bid-512)*8;
    kf_pre<2>(act,smem,b0);
    const unsigned* Aw=(const unsigned*)(A+ABASE(1));
    kf_triple<1,0,1,0,2>(sa_,bt,Aw,cR,cI);
    kf_triple<1,1,1,1,2>(sa_,bt,Aw,cR,cI);
    kf_triple<2,1,1,2,2>(sa_,bt,Aw,cR,cI);
    kf_triple<2,2,1,3,2>(sa_,bt,Aw,cR,cI);
    kf_triple<3,2,1,4,2>(sa_,bt,Aw,cR,cI);
    kf_triple<3,3,1,5,2>(sa_,bt,Aw,cR,cI);
    kf_epi<1,2>(out,b0,cR,cI);
  } else {                                                // l=0, rows 8, NTIL 1
    const int b0 = (bid-768)*8;
    kf_pre<1>(act,smem,b0);
    const unsigned* Aw=(const unsigned*)(A+ABASE(0));
    kf_triple<0,0,0,0,1>(sa_,bt,Aw,cR,cI);
    kf_triple<1,1,0,1,1>(sa_,bt,Aw,cR,cI);
    kf_triple<2,2,0,2,1>(sa_,bt,Aw,cR,cI);
    kf_triple<3,3,0,3,1>(sa_,bt,Aw,cR,cI);
    kf_epi<0,1>(out,b0,cR,cI);
  }
}

// ================= host launch =================
extern "C" void kernel_launch(void* const* d_in, const int* in_sizes, int n_in,
                              void* d_out, int out_size, void* d_ws, size_t ws_size,
                              hipStream_t stream) {
  const float* act = (const float*)d_in[0];   // (2048,256,2) f32
  const float* W   = (const float*)d_in[1];   // (94208,2) f32
  const float* bn  = (const float*)d_in[2];   // (5888,) f32
  float* out = (float*)d_out;                 // (2048,256,2) f32

  float* sumsq = (float*)d_ws;                          // 5888 f32
  short* A     = (short*)((char*)d_ws + 24576);         // 376832 bf16 (754 KB)

  hipMemsetAsync(sumsq, 0, 5888*sizeof(float), stream);
  hipLaunchKernelGGL(k_sumsq,   dim3(23*128), dim3(256), 0, stream, act, sumsq);
  hipLaunchKernelGGL(k_buildA,  dim3(23),     dim3(256), 0, stream, W, bn, sumsq, A);
  hipLaunchKernelGGL(k_fusedall,dim3(1024),   dim3(256), 0, stream, act, A, out);
}

// Round 4
// 207.081 us; speedup vs baseline: 1.7142x; 1.0905x over previous
//
#include <hip/hip_runtime.h>
#include <math.h>

typedef __attribute__((ext_vector_type(8))) short bf16x8;
typedef __attribute__((ext_vector_type(4))) float f32x4;

// ================= compile-time Clebsch-Gordan tables =================
constexpr double cfact(int n){ double r=1.0; for(int i=2;i<=n;++i) r*=(double)i; return r; }
constexpr double csqrt_(double x){ double g=(x>1.0)?x:1.0; for(int i=0;i<100;++i) g=0.5*(g+x/g); return g; }
constexpr double cg_coef_(int l1,int m1,int l2,int m2,int l,int m){
  double pre = csqrt_((double)(2*l+1)*cfact(l1+l2-l)*cfact(l1-l2+l)*cfact(-l1+l2+l)/cfact(l1+l2+l+1));
  pre = pre*csqrt_(cfact(l+m)*cfact(l-m)*cfact(l1-m1)*cfact(l1+m1)*cfact(l2-m2)*cfact(l2+m2));
  double s=0.0;
  for(int k=0;k<=l1+l2-l;++k){
    int d0=k,d1=l1+l2-l-k,d2=l1-m1-k,d3=l2+m2-k,d4=l-l2+m1+k,d5=l-l1-m2+k;
    if(d0<0||d1<0||d2<0||d3<0||d4<0||d5<0) continue;
    double den=cfact(d0)*cfact(d1)*cfact(d2)*cfact(d3)*cfact(d4)*cfact(d5);
    s+=((k&1)?-1.0:1.0)/den;
  }
  return pre*s;
}
struct CGList{ int n; float coef[64]; int mi[64]; int ni[64]; int pi[64]; };
constexpr CGList build_cg(int l1,int l2,int l){
  CGList T{};
  for(int i=0;i<2*l1+1;++i){
    for(int j=0;j<2*l2+1;++j){
      int m1=i-l1, m2=j-l2, m=m1+m2;
      if(m<-l||m>l) continue;
      double c=cg_coef_(l1,m1,l2,m2,l,m);
      if(c>1e-12||c<-1e-12){
        T.coef[T.n]=(float)c; T.mi[T.n]=i; T.ni[T.n]=j; T.pi[T.n]=m+l; T.n++;
      }
    }
  }
  return T;
}

// ================= layout constants =================
__device__ __host__ constexpr int AOFF(int l){ return l==0?0: l==1?16: l==2?64:144; }
__device__ __host__ constexpr int MLs(int l){ return l==0?1024: l==1?1536: l==2?1792:1536; }
__device__ __host__ constexpr int WOFF(int l){ return l==0?0: l==1?16384: l==2?40960:69632; }
__device__ __host__ constexpr int SOFF(int l){ return l==0?0: l==1?1024: l==2?2560:4352; }
__device__ __host__ constexpr int ABASE(int l){ return l==0?0: l==1?65536: l==2?163840:278528; }

#define DEVFN __device__ __forceinline__
#define BP 68    // btile row pitch in words
#define AP 68    // ldsA row pitch in words

DEVFN unsigned f2bf2(float x, float y){
  unsigned ux = __float_as_uint(x); ux = (ux + 0x7FFFu + ((ux>>16)&1u)) >> 16;
  unsigned uy = __float_as_uint(y); uy = (uy + 0x7FFFu + ((uy>>16)&1u)) >> 16;
  return (ux & 0xFFFFu) | (uy << 16);
}

template<int L1,int L2,int L>
DEVFN void cg_accum(const float2* F1, const float2* F2, float2* mid){
  constexpr CGList T = build_cg(L1,L2,L);
  #pragma unroll
  for(int e=0;e<T.n;++e){
    const float c = T.coef[e];
    const float2 a = F1[T.mi[e]];
    const float2 b = F2[T.ni[e]];
    float pr = a.x*b.x - a.y*b.y;
    float pim= a.x*b.y + a.y*b.x;
    mid[T.pi[e]].x += c*pr;
    mid[T.pi[e]].y += c*pim;
  }
}

// ===== K1: sum-of-squares, 8 batches/block (16 KB LDS -> more blocks/CU) =====
template<int L1,int L2,int L>
DEVFN void k1_body(const float2* __restrict__ acts, int u, int bh,
                   float& ssa, float& ssb){
  constexpr int N1=2*L1+1, N2=2*L2+1, NP=2*L+1;
  const int t = u>>3, s0 = (u&7)*2;
  #pragma unroll 2
  for(int bi=0;bi<4;++bi){
    const int row = bh*4 + bi;
    const float2* arow = acts + row*256;
    float2 F1[N1], F2a[N2], F2b[N2], mida[NP], midb[NP];
    #pragma unroll
    for(int m=0;m<N1;++m) F1[m]=arow[AOFF(L1)+t*N1+m];
    #pragma unroll
    for(int n=0;n<N2;++n){
      F2a[n]=arow[AOFF(L2)+s0*N2+n];
      F2b[n]=arow[AOFF(L2)+(s0+1)*N2+n];
    }
    #pragma unroll
    for(int p=0;p<NP;++p){ mida[p]=make_float2(0.f,0.f); midb[p]=make_float2(0.f,0.f); }
    cg_accum<L1,L2,L>(F1,F2a,mida);
    cg_accum<L1,L2,L>(F1,F2b,midb);
    #pragma unroll
    for(int p=0;p<NP;++p){
      ssa += mida[p].x*mida[p].x + mida[p].y*mida[p].y;
      ssb += midb[p].x*midb[p].x + midb[p].y*midb[p].y;
    }
  }
}

__global__ __launch_bounds__(256) void k_sumsq(const float* __restrict__ act,
                                               float* __restrict__ sumsq){
  __shared__ float2 acts[8*256];             // 16 KB: 8 act rows
  int bid=blockIdx.x;                        // 23 triples * 256 chunks
  const int order[23] = {22,16,21,18,15,20,13,9,14,8,17,7,12,6,10,3,5,19,2,11,1,4,0};
  int ti = order[bid>>8];
  int b0 = (bid&255)*8;
  const int tid = threadIdx.x;
  {
    const float4* ag = (const float4*)act + (size_t)b0*128;
    float4* as4 = (float4*)acts;
    #pragma unroll
    for(int j=0;j<4;++j) as4[j*256+tid] = ag[j*256+tid];
  }
  __syncthreads();
  const int u = tid & 127, bh = tid >> 7;    // channels (2u,2u+1), b-half bh
  float ssa=0.f, ssb=0.f;
  switch(ti){
    case 0:  k1_body<0,0,0>(acts,u,bh,ssa,ssb); break;
    case 1:  k1_body<1,1,0>(acts,u,bh,ssa,ssb); break;
    case 2:  k1_body<2,2,0>(acts,u,bh,ssa,ssb); break;
    case 3:  k1_body<3,3,0>(acts,u,bh,ssa,ssb); break;
    case 4:  k1_body<1,0,1>(acts,u,bh,ssa,ssb); break;
    case 5:  k1_body<1,1,1>(acts,u,bh,ssa,ssb); break;
    case 6:  k1_body<2,1,1>(acts,u,bh,ssa,ssb); break;
    case 7:  k1_body<2,2,1>(acts,u,bh,ssa,ssb); break;
    case 8:  k1_body<3,2,1>(acts,u,bh,ssa,ssb); break;
    case 9:  k1_body<3,3,1>(acts,u,bh,ssa,ssb); break;
    case 10: k1_body<1,1,2>(acts,u,bh,ssa,ssb); break;
    case 11: k1_body<2,0,2>(acts,u,bh,ssa,ssb); break;
    case 12: k1_body<2,1,2>(acts,u,bh,ssa,ssb); break;
    case 13: k1_body<2,2,2>(acts,u,bh,ssa,ssb); break;
    case 14: k1_body<3,1,2>(acts,u,bh,ssa,ssb); break;
    case 15: k1_body<3,2,2>(acts,u,bh,ssa,ssb); break;
    case 16: k1_body<3,3,2>(acts,u,bh,ssa,ssb); break;
    case 17: k1_body<2,1,3>(acts,u,bh,ssa,ssb); break;
    case 18: k1_body<2,2,3>(acts,u,bh,ssa,ssb); break;
    case 19: k1_body<3,0,3>(acts,u,bh,ssa,ssb); break;
    case 20: k1_body<3,1,3>(acts,u,bh,ssa,ssb); break;
    case 21: k1_body<3,2,3>(acts,u,bh,ssa,ssb); break;
    default: k1_body<3,3,3>(acts,u,bh,ssa,ssb); break;
  }
  atomicAdd(&sumsq[ti*256 + 2*u],     ssa);
  atomicAdd(&sumsq[ti*256 + 2*u + 1], ssb);
}

// ============ K2: scale + build bf16 A matrices (scale folded into W) =======
__global__ __launch_bounds__(256) void k_buildA(const float* __restrict__ W,
                                                const float* __restrict__ bn,
                                                const float* __restrict__ sumsq,
                                                short* __restrict__ A){
  int idx = blockIdx.x*256 + threadIdx.x;   // 5888 channels
  if(idx>=5888) return;
  int l = (idx<1024)?0 : (idx<2560)?1 : (idx<4352)?2 : 3;
  float divi = (l==0)?(1.f/2048.f) : (l==1)?(1.f/6144.f) : (l==2)?(1.f/10240.f) : (1.f/14336.f);
  float bstd = sqrtf(sumsq[idx]*divi);
  float nstd = 0.5f*(bn[idx]+bstd);
  float s = 1.f/(nstd+1e-5f);
  int c = idx - SOFF(l);
  int Ml = MLs(l);
  const float2* wbase = (const float2*)W + WOFF(l) + c;
  unsigned* Aw = (unsigned*)(A + ABASE(l));   // row pitch = Ml words (2*Ml bf16)
  for(int o=0;o<16;++o){
    float2 w = wbase[(size_t)o*Ml];
    Aw[(size_t)o*Ml + c]      = f2bf2(w.x*s, -w.y*s);
    Aw[(size_t)(o+16)*Ml + c] = f2bf2(w.y*s,  w.x*s);
  }
}

// ======== K3: fused recompute-GEMM, merged (all l in one launch) ========
// Block = 8 batches of one l. Per 64-word chunk:
//   { coalesced A-chunk stage -> ldsA (latency hides under phase1 VALU);
//     phase1 CG recompute -> btile; barrier;
//     MFMA (A from ldsA, B from btile); barrier }
// Full-K register accumulation -> single float2 store per output element.
// No register A-prefetch (spill fix); LDS 42.5 KB -> 3 blocks/CU.

// LDS layout (bytes): [0,16384) sa | [16384,33792) btile | [33792,42496) ldsA
#define SA_B   0
#define BT_B   16384
#define LA_B   33792

template<int NTIL>
DEVFN void kf_pre(const float* __restrict__ act, char* smem, int b0){
  const int tid = threadIdx.x;
  const float2* actg2 = (const float2*)act + (size_t)b0*256;
  float4* s4 = (float4*)(smem + SA_B);
  const float4* ag = (const float4*)actg2;
  #pragma unroll
  for(int j=0;j<4;++j) s4[j*256+tid] = ag[j*256+tid];
  unsigned* btile = (unsigned*)(smem + BT_B);
  for(int i=tid; i<NTIL*16*BP; i+=256) btile[i]=0;
  __syncthreads();
}

template<int L1,int L2,int L,int Q,int NTIL>
DEVFN void kf_triple(char* smem, const unsigned* __restrict__ Aw,
                     f32x4& cR, f32x4& cI){
  constexpr int N1=2*L1+1, N2=2*L2+1, NP=2*L+1;
  constexpr int Ml = MLs(L);
  const float2* sa = (const float2*)(smem + SA_B);
  unsigned* btile  = (unsigned*)(smem + BT_B);
  unsigned* ldsA   = (unsigned*)(smem + LA_B);
  const int tid = threadIdx.x;
  const int lane = tid & 63, w = tid >> 6;
  const int col = lane & 15, quad = lane >> 4;
  const int up = tid & 31, bi = tid >> 5;    // channel-pair-in-chunk, batch
  #pragma unroll 1
  for(int cc=0; cc<4; ++cc){
    // ---- stage A chunk [32][64w] -> ldsA (coalesced; hides under phase1) ----
    {
      const int base = (Q*4+cc)*64;
      const int r0 = tid>>4,        j0 = (tid&15)*4;
      const int r1 = (tid+256)>>4,  j1 = j0;
      uint4 v0 = *(const uint4*)(Aw + (size_t)r0*Ml + base + j0);
      uint4 v1 = *(const uint4*)(Aw + (size_t)r1*Ml + base + j1);
      *(uint4*)(ldsA + r0*AP + j0) = v0;
      *(uint4*)(ldsA + r1*AP + j1) = v1;
    }
    // ---- phase1: CG recompute for 64 K-words x 8 batches -> btile ----
    {
      const int u = cc*32 + up;              // channel pair (2u,2u+1)
      const int t = u>>3, s0 = (u&7)*2;
      const float2* arow = sa + bi*256;
      float2 F1[N1], F2a[N2], F2b[N2], mida[NP], midb[NP];
      #pragma unroll
      for(int m=0;m<N1;++m) F1[m]=arow[AOFF(L1)+t*N1+m];
      #pragma unroll
      for(int n=0;n<N2;++n){
        F2a[n]=arow[AOFF(L2)+s0*N2+n];
        F2b[n]=arow[AOFF(L2)+(s0+1)*N2+n];
      }
      #pragma unroll
      for(int p=0;p<NP;++p){ mida[p]=make_float2(0.f,0.f); midb[p]=make_float2(0.f,0.f); }
      cg_accum<L1,L2,L>(F1,F2a,mida);
      cg_accum<L1,L2,L>(F1,F2b,midb);
      #pragma unroll
      for(int p=0;p<NP;++p){
        uint2 v; v.x = f2bf2(mida[p].x, mida[p].y); v.y = f2bf2(midb[p].x, midb[p].y);
        *(uint2*)(btile + (size_t)(bi*NP+p)*BP + 2*up) = v;
      }
    }
    __syncthreads();
    // ---- MFMA accumulate (A and B both from LDS) ----
    if(w < NTIL){
      const unsigned* ar0 = ldsA + col*AP + quad*4;
      const unsigned* ar1 = ldsA + (col+16)*AP + quad*4;
      const unsigned* bb  = btile + (w*16+col)*BP + quad*4;
      #pragma unroll
      for(int ks=0; ks<4; ++ks){
        bf16x8 b  = *(const bf16x8*)(bb + ks*16);
        bf16x8 A0 = *(const bf16x8*)(ar0 + ks*16);
        bf16x8 A1 = *(const bf16x8*)(ar1 + ks*16);
        cR = __builtin_amdgcn_mfma_f32_16x16x32_bf16(A0, b, cR, 0, 0, 0);
        cI = __builtin_amdgcn_mfma_f32_16x16x32_bf16(A1, b, cI, 0, 0, 0);
      }
    }
    __syncthreads();
  }
}

template<int L,int NTIL>
DEVFN void kf_epi(float* __restrict__ out, int b0, f32x4 cR, f32x4 cI){
  constexpr int NP = 2*L+1;
  const int tid = threadIdx.x, lane = tid & 63, w = tid >> 6;
  const int col = lane & 15, quad = lane >> 4;
  if(w < NTIL){
    const int r = w*16 + col;
    if(r < 8*NP){
      const int b = b0 + r/NP, p = r - (r/NP)*NP;
      float2* o2 = (float2*)out + (size_t)b*256 + AOFF(L);
      #pragma unroll
      for(int i=0;i<4;++i) o2[(quad*4+i)*NP + p] = make_float2(cR[i], cI[i]);
    }
  }
}

__global__ __launch_bounds__(256,3) void k_fusedall(const float* __restrict__ act,
    const short* __restrict__ A, float* __restrict__ out){
  __shared__ __align__(16) char smem[42496];
  const int bid = blockIdx.x;                             // 1024
  f32x4 cR={0.f,0.f,0.f,0.f}, cI={0.f,0.f,0.f,0.f};
  if(bid < 256){                                          // l=3, rows 56, NTIL 4
    const int b0 = bid*8;
    kf_pre<4>(act,smem,b0);
    const unsigned* Aw=(const unsigned*)(A+ABASE(3));
    kf_triple<2,1,3,0,4>(smem,Aw,cR,cI);
    kf_triple<2,2,3,1,4>(smem,Aw,cR,cI);
    kf_triple<3,0,3,2,4>(smem,Aw,cR,cI);
    kf_triple<3,1,3,3,4>(smem,Aw,cR,cI);
    kf_triple<3,2,3,4,4>(smem,Aw,cR,cI);
    kf_triple<3,3,3,5,4>(smem,Aw,cR,cI);
    kf_epi<3,4>(out,b0,cR,cI);
  } else if(bid < 512){                                   // l=2, rows 40, NTIL 3
    const int b0 = (bid-256)*8;
    kf_pre<3>(act,smem,b0);
    const unsigned* Aw=(const unsigned*)(A+ABASE(2));
    kf_triple<1,1,2,0,3>(smem,Aw,cR,cI);
    kf_triple<2,0,2,1,3>(smem,Aw,cR,cI);
    kf_triple<2,1,2,2,3>(smem,Aw,cR,cI);
    kf_triple<2,2,2,3,3>(smem,Aw,cR,cI);
    kf_triple<3,1,2,4,3>(smem,Aw,cR,cI);
    kf_triple<3,2,2,5,3>(smem,Aw,cR,cI);
    kf_triple<3,3,2,6,3>(smem,Aw,cR,cI);
    kf_epi<2,3>(out,b0,cR,cI);
  } else if(bid < 768){                                   // l=1, rows 24, NTIL 2
    const int b0 = (bid-512)*8;
    kf_pre<2>(act,smem,b0);
    const unsigned* Aw=(const unsigned*)(A+ABASE(1));
    kf_triple<1,0,1,0,2>(smem,Aw,cR,cI);
    kf_triple<1,1,1,1,2>(smem,Aw,cR,cI);
    kf_triple<2,1,1,2,2>(smem,Aw,cR,cI);
    kf_triple<2,2,1,3,2>(smem,Aw,cR,cI);
    kf_triple<3,2,1,4,2>(smem,Aw,cR,cI);
    kf_triple<3,3,1,5,2>(smem,Aw,cR,cI);
    kf_epi<1,2>(out,b0,cR,cI);
  } else {                                                // l=0, rows 8, NTIL 1
    const int b0 = (bid-768)*8;
    kf_pre<1>(act,smem,b0);
    const unsigned* Aw=(const unsigned*)(A+ABASE(0));
    kf_triple<0,0,0,0,1>(smem,Aw,cR,cI);
    kf_triple<1,1,0,1,1>(smem,Aw,cR,cI);
    kf_triple<2,2,0,2,1>(smem,Aw,cR,cI);
    kf_triple<3,3,0,3,1>(smem,Aw,cR,cI);
    kf_epi<0,1>(out,b0,cR,cI);
  }
}

// ================= host launch =================
extern "C" void kernel_launch(void* const* d_in, const int* in_sizes, int n_in,
                              void* d_out, int out_size, void* d_ws, size_t ws_size,
                              hipStream_t stream) {
  const float* act = (const float*)d_in[0];   // (2048,256,2) f32
  const float* W   = (const float*)d_in[1];   // (94208,2) f32
  const float* bn  = (const float*)d_in[2];   // (5888,) f32
  float* out = (float*)d_out;                 // (2048,256,2) f32

  float* sumsq = (float*)d_ws;                          // 5888 f32
  short* A     = (short*)((char*)d_ws + 24576);         // 376832 bf16 (754 KB)

  hipMemsetAsync(sumsq, 0, 5888*sizeof(float), stream);
  hipLaunchKernelGGL(k_sumsq,   dim3(23*256), dim3(256), 0, stream, act, sumsq);
  hipLaunchKernelGGL(k_buildA,  dim3(23),     dim3(256), 0, stream, W, bn, sumsq, A);
  hipLaunchKernelGGL(k_fusedall,dim3(1024),   dim3(256), 0, stream, act, A, out);
}

// Round 5
// 144.736 us; speedup vs baseline: 2.4526x; 1.4308x over previous
//
#include <hip/hip_runtime.h>
#include <math.h>

typedef __attribute__((ext_vector_type(8))) short bf16x8;
typedef __attribute__((ext_vector_type(4))) float f32x4;

// ================= compile-time Clebsch-Gordan tables =================
constexpr double cfact(int n){ double r=1.0; for(int i=2;i<=n;++i) r*=(double)i; return r; }
constexpr double csqrt_(double x){ double g=(x>1.0)?x:1.0; for(int i=0;i<100;++i) g=0.5*(g+x/g); return g; }
constexpr double cg_coef_(int l1,int m1,int l2,int m2,int l,int m){
  double pre = csqrt_((double)(2*l+1)*cfact(l1+l2-l)*cfact(l1-l2+l)*cfact(-l1+l2+l)/cfact(l1+l2+l+1));
  pre = pre*csqrt_(cfact(l+m)*cfact(l-m)*cfact(l1-m1)*cfact(l1+m1)*cfact(l2-m2)*cfact(l2+m2));
  double s=0.0;
  for(int k=0;k<=l1+l2-l;++k){
    int d0=k,d1=l1+l2-l-k,d2=l1-m1-k,d3=l2+m2-k,d4=l-l2+m1+k,d5=l-l1-m2+k;
    if(d0<0||d1<0||d2<0||d3<0||d4<0||d5<0) continue;
    double den=cfact(d0)*cfact(d1)*cfact(d2)*cfact(d3)*cfact(d4)*cfact(d5);
    s+=((k&1)?-1.0:1.0)/den;
  }
  return pre*s;
}
struct CGList{ int n; float coef[64]; int mi[64]; int ni[64]; int pi[64]; };
constexpr CGList build_cg(int l1,int l2,int l){
  CGList T{};
  for(int i=0;i<2*l1+1;++i){
    for(int j=0;j<2*l2+1;++j){
      int m1=i-l1, m2=j-l2, m=m1+m2;
      if(m<-l||m>l) continue;
      double c=cg_coef_(l1,m1,l2,m2,l,m);
      if(c>1e-12||c<-1e-12){
        T.coef[T.n]=(float)c; T.mi[T.n]=i; T.ni[T.n]=j; T.pi[T.n]=m+l; T.n++;
      }
    }
  }
  return T;
}

// ================= layout constants =================
__device__ __host__ constexpr int AOFF(int l){ return l==0?0: l==1?16: l==2?64:144; }
__device__ __host__ constexpr int MLs(int l){ return l==0?1024: l==1?1536: l==2?1792:1536; }
__device__ __host__ constexpr int WOFF(int l){ return l==0?0: l==1?16384: l==2?40960:69632; }
__device__ __host__ constexpr int SOFF(int l){ return l==0?0: l==1?1024: l==2?2560:4352; }
__device__ __host__ constexpr int ABASE(int l){ return l==0?0: l==1?65536: l==2?163840:278528; }

#define DEVFN __device__ __forceinline__
#define BP 68    // btile row pitch in words
#define AP 68    // ldsA row pitch in words

DEVFN unsigned f2bf2(float x, float y){
  unsigned ux = __float_as_uint(x); ux = (ux + 0x7FFFu + ((ux>>16)&1u)) >> 16;
  unsigned uy = __float_as_uint(y); uy = (uy + 0x7FFFu + ((uy>>16)&1u)) >> 16;
  return (ux & 0xFFFFu) | (uy << 16);
}

template<int L1,int L2,int L>
DEVFN void cg_accum(const float2* F1, const float2* F2, float2* mid){
  constexpr CGList T = build_cg(L1,L2,L);
  #pragma unroll
  for(int e=0;e<T.n;++e){
    const float c = T.coef[e];
    const float2 a = F1[T.mi[e]];
    const float2 b = F2[T.ni[e]];
    float pr = a.x*b.x - a.y*b.y;
    float pim= a.x*b.y + a.y*b.x;
    mid[T.pi[e]].x += c*pr;
    mid[T.pi[e]].y += c*pim;
  }
}

// ===== K1: sum-of-squares partials — 64 batches/block, NO atomics =====
template<int L1,int L2,int L>
DEVFN void k1_body(const float2* __restrict__ acts, int u, int bh,
                   float& ssa, float& ssb){
  constexpr int N1=2*L1+1, N2=2*L2+1, NP=2*L+1;
  const int t = u>>3, s0 = (u&7)*2;
  #pragma unroll 2
  for(int bi=0;bi<8;++bi){
    const int row = bh*8 + bi;
    const float2* arow = acts + row*256;
    float2 F1[N1], F2a[N2], F2b[N2], mida[NP], midb[NP];
    #pragma unroll
    for(int m=0;m<N1;++m) F1[m]=arow[AOFF(L1)+t*N1+m];
    #pragma unroll
    for(int n=0;n<N2;++n){
      F2a[n]=arow[AOFF(L2)+s0*N2+n];
      F2b[n]=arow[AOFF(L2)+(s0+1)*N2+n];
    }
    #pragma unroll
    for(int p=0;p<NP;++p){ mida[p]=make_float2(0.f,0.f); midb[p]=make_float2(0.f,0.f); }
    cg_accum<L1,L2,L>(F1,F2a,mida);
    cg_accum<L1,L2,L>(F1,F2b,midb);
    #pragma unroll
    for(int p=0;p<NP;++p){
      ssa += mida[p].x*mida[p].x + mida[p].y*mida[p].y;
      ssb += midb[p].x*midb[p].x + midb[p].y*midb[p].y;
    }
  }
}

template<int L1,int L2,int L>
DEVFN void k1_quad(const float* __restrict__ act, float2* acts, int b0,
                   int u, int bh, float& ssa, float& ssb){
  const int tid = threadIdx.x;
  for(int seg=0; seg<4; ++seg){
    const float4* ag = (const float4*)act + (size_t)(b0+seg*16)*128;
    float4* as4 = (float4*)acts;
    #pragma unroll
    for(int j=0;j<8;++j) as4[j*256+tid] = ag[j*256+tid];
    __syncthreads();
    k1_body<L1,L2,L>(acts,u,bh,ssa,ssb);
    __syncthreads();
  }
}

__global__ __launch_bounds__(256) void k_sumsq(const float* __restrict__ act,
                                               float2* __restrict__ part){
  __shared__ float2 acts[16*256];            // 32 KB: 16 act rows
  int bid=blockIdx.x;                        // 23 triples * 32 chunks (64 batches)
  const int order[23] = {22,16,21,18,15,20,13,9,14,8,17,7,12,6,10,3,5,19,2,11,1,4,0};
  int ti = order[bid>>5];
  int chunk = bid&31;
  int b0 = chunk*64;
  const int tid = threadIdx.x;
  const int u = tid & 127, bh = tid >> 7;    // channels (2u,2u+1), b-half bh
  float ssa=0.f, ssb=0.f;
  switch(ti){
    case 0:  k1_quad<0,0,0>(act,acts,b0,u,bh,ssa,ssb); break;
    case 1:  k1_quad<1,1,0>(act,acts,b0,u,bh,ssa,ssb); break;
    case 2:  k1_quad<2,2,0>(act,acts,b0,u,bh,ssa,ssb); break;
    case 3:  k1_quad<3,3,0>(act,acts,b0,u,bh,ssa,ssb); break;
    case 4:  k1_quad<1,0,1>(act,acts,b0,u,bh,ssa,ssb); break;
    case 5:  k1_quad<1,1,1>(act,acts,b0,u,bh,ssa,ssb); break;
    case 6:  k1_quad<2,1,1>(act,acts,b0,u,bh,ssa,ssb); break;
    case 7:  k1_quad<2,2,1>(act,acts,b0,u,bh,ssa,ssb); break;
    case 8:  k1_quad<3,2,1>(act,acts,b0,u,bh,ssa,ssb); break;
    case 9:  k1_quad<3,3,1>(act,acts,b0,u,bh,ssa,ssb); break;
    case 10: k1_quad<1,1,2>(act,acts,b0,u,bh,ssa,ssb); break;
    case 11: k1_quad<2,0,2>(act,acts,b0,u,bh,ssa,ssb); break;
    case 12: k1_quad<2,1,2>(act,acts,b0,u,bh,ssa,ssb); break;
    case 13: k1_quad<2,2,2>(act,acts,b0,u,bh,ssa,ssb); break;
    case 14: k1_quad<3,1,2>(act,acts,b0,u,bh,ssa,ssb); break;
    case 15: k1_quad<3,2,2>(act,acts,b0,u,bh,ssa,ssb); break;
    case 16: k1_quad<3,3,2>(act,acts,b0,u,bh,ssa,ssb); break;
    case 17: k1_quad<2,1,3>(act,acts,b0,u,bh,ssa,ssb); break;
    case 18: k1_quad<2,2,3>(act,acts,b0,u,bh,ssa,ssb); break;
    case 19: k1_quad<3,0,3>(act,acts,b0,u,bh,ssa,ssb); break;
    case 20: k1_quad<3,1,3>(act,acts,b0,u,bh,ssa,ssb); break;
    case 21: k1_quad<3,2,3>(act,acts,b0,u,bh,ssa,ssb); break;
    default: k1_quad<3,3,3>(act,acts,b0,u,bh,ssa,ssb); break;
  }
  // plain coalesced store of the block's partials (no atomics)
  part[(size_t)((ti*32 + chunk)*2 + bh)*128 + u] = make_float2(ssa, ssb);
}

// ==== K2: reduce partials + scale + build bf16 A (scale folded into W) ====
__global__ __launch_bounds__(256) void k_buildA(const float* __restrict__ W,
                                                const float* __restrict__ bn,
                                                const float2* __restrict__ part,
                                                short* __restrict__ A){
  int idx = blockIdx.x*256 + threadIdx.x;   // 5888 channels
  if(idx>=5888) return;
  int ti = idx>>8, ch = idx&255, u = ch>>1;
  const float2* ps = part + (size_t)(ti*64)*128 + u;
  float sum = 0.f;
  #pragma unroll 8
  for(int j=0;j<64;++j){
    float2 v = ps[(size_t)j*128];
    sum += (ch&1) ? v.y : v.x;
  }
  int l = (idx<1024)?0 : (idx<2560)?1 : (idx<4352)?2 : 3;
  float divi = (l==0)?(1.f/2048.f) : (l==1)?(1.f/6144.f) : (l==2)?(1.f/10240.f) : (1.f/14336.f);
  float bstd = sqrtf(sum*divi);
  float nstd = 0.5f*(bn[idx]+bstd);
  float s = 1.f/(nstd+1e-5f);
  int c = idx - SOFF(l);
  int Ml = MLs(l);
  const float2* wbase = (const float2*)W + WOFF(l) + c;
  unsigned* Aw = (unsigned*)(A + ABASE(l));   // row pitch = Ml words (2*Ml bf16)
  for(int o=0;o<16;++o){
    float2 w = wbase[(size_t)o*Ml];
    Aw[(size_t)o*Ml + c]      = f2bf2(w.x*s, -w.y*s);
    Aw[(size_t)(o+16)*Ml + c] = f2bf2(w.y*s,  w.x*s);
  }
}

// ======== K3: fused recompute-GEMM, merged (all l in one launch) ========
// Block = 8 batches of one l. Per 64-word chunk (double-buffered ldsA):
//   { issue global loads for chunk cc+1;
//     phase1 CG recompute chunk cc -> btile  (~600 cyc hides the loads);
//     vmcnt-wait + ds_write chunk cc+1 -> other ldsA buffer; barrier;
//     MFMA chunk cc (A from ldsA[cc&1], B from btile); barrier }
// Full-K register accumulation -> single float2 store per output element.

// LDS layout (bytes): [0,16384) sa | [16384,33792) btile | [33792,51200) ldsA x2
#define SA_B   0
#define BT_B   16384
#define LA_B   33792

template<int NTIL>
DEVFN void kf_pre(const float* __restrict__ act, char* smem, int b0){
  const int tid = threadIdx.x;
  const float2* actg2 = (const float2*)act + (size_t)b0*256;
  float4* s4 = (float4*)(smem + SA_B);
  const float4* ag = (const float4*)actg2;
  #pragma unroll
  for(int j=0;j<4;++j) s4[j*256+tid] = ag[j*256+tid];
  unsigned* btile = (unsigned*)(smem + BT_B);
  for(int i=tid; i<NTIL*16*BP; i+=256) btile[i]=0;
  __syncthreads();
}

template<int L1,int L2,int L,int Q,int NTIL>
DEVFN void kf_triple(char* smem, const unsigned* __restrict__ Aw,
                     f32x4& cR, f32x4& cI){
  constexpr int N1=2*L1+1, N2=2*L2+1, NP=2*L+1;
  constexpr int Ml = MLs(L);
  const float2* sa = (const float2*)(smem + SA_B);
  unsigned* btile  = (unsigned*)(smem + BT_B);
  unsigned* ldsA   = (unsigned*)(smem + LA_B);
  const int tid = threadIdx.x;
  const int lane = tid & 63, w = tid >> 6;
  const int col = lane & 15, quad = lane >> 4;
  const int up = tid & 31, bi = tid >> 5;    // channel-pair-in-chunk, batch
  const int r0 = tid>>4,       j0 = (tid&15)*4;
  const int r1 = (tid+256)>>4;
  // prologue: stage chunk 0 into buffer 0 (latency exposed once per triple)
  {
    const int base = (Q*4)*64;
    uint4 v0 = *(const uint4*)(Aw + (size_t)r0*Ml + base + j0);
    uint4 v1 = *(const uint4*)(Aw + (size_t)r1*Ml + base + j0);
    *(uint4*)(ldsA + r0*AP + j0) = v0;
    *(uint4*)(ldsA + r1*AP + j0) = v1;
  }
  #pragma unroll 1
  for(int cc=0; cc<4; ++cc){
    unsigned* cbuf = ldsA + (cc&1)*(32*AP);
    unsigned* nbuf = ldsA + ((cc+1)&1)*(32*AP);
    // ---- issue next A-chunk loads (completion hidden under phase1) ----
    uint4 v0, v1;
    if(cc<3){
      const int base = (Q*4+cc+1)*64;
      v0 = *(const uint4*)(Aw + (size_t)r0*Ml + base + j0);
      v1 = *(const uint4*)(Aw + (size_t)r1*Ml + base + j0);
    }
    // ---- phase1: CG recompute for 64 K-words x 8 batches -> btile ----
    {
      const int u = cc*32 + up;              // channel pair (2u,2u+1)
      const int t = u>>3, s0 = (u&7)*2;
      const float2* arow = sa + bi*256;
      float2 F1[N1], F2a[N2], F2b[N2], mida[NP], midb[NP];
      #pragma unroll
      for(int m=0;m<N1;++m) F1[m]=arow[AOFF(L1)+t*N1+m];
      #pragma unroll
      for(int n=0;n<N2;++n){
        F2a[n]=arow[AOFF(L2)+s0*N2+n];
        F2b[n]=arow[AOFF(L2)+(s0+1)*N2+n];
      }
      #pragma unroll
      for(int p=0;p<NP;++p){ mida[p]=make_float2(0.f,0.f); midb[p]=make_float2(0.f,0.f); }
      cg_accum<L1,L2,L>(F1,F2a,mida);
      cg_accum<L1,L2,L>(F1,F2b,midb);
      #pragma unroll
      for(int p=0;p<NP;++p){
        uint2 v; v.x = f2bf2(mida[p].x, mida[p].y); v.y = f2bf2(midb[p].x, midb[p].y);
        *(uint2*)(btile + (size_t)(bi*NP+p)*BP + 2*up) = v;
      }
    }
    // ---- land next A-chunk into the buffer MFMA won't read this chunk ----
    if(cc<3){
      *(uint4*)(nbuf + r0*AP + j0) = v0;
      *(uint4*)(nbuf + r1*AP + j0) = v1;
    }
    __syncthreads();
    // ---- MFMA accumulate (A and B both from LDS) ----
    if(w < NTIL){
      const unsigned* ar0 = cbuf + col*AP + quad*4;
      const unsigned* ar1 = cbuf + (col+16)*AP + quad*4;
      const unsigned* bb  = btile + (w*16+col)*BP + quad*4;
      #pragma unroll
      for(int ks=0; ks<4; ++ks){
        bf16x8 b  = *(const bf16x8*)(bb + ks*16);
        bf16x8 A0 = *(const bf16x8*)(ar0 + ks*16);
        bf16x8 A1 = *(const bf16x8*)(ar1 + ks*16);
        cR = __builtin_amdgcn_mfma_f32_16x16x32_bf16(A0, b, cR, 0, 0, 0);
        cI = __builtin_amdgcn_mfma_f32_16x16x32_bf16(A1, b, cI, 0, 0, 0);
      }
    }
    __syncthreads();
  }
}

template<int L,int NTIL>
DEVFN void kf_epi(float* __restrict__ out, int b0, f32x4 cR, f32x4 cI){
  constexpr int NP = 2*L+1;
  const int tid = threadIdx.x, lane = tid & 63, w = tid >> 6;
  const int col = lane & 15, quad = lane >> 4;
  if(w < NTIL){
    const int r = w*16 + col;
    if(r < 8*NP){
      const int b = b0 + r/NP, p = r - (r/NP)*NP;
      float2* o2 = (float2*)out + (size_t)b*256 + AOFF(L);
      #pragma unroll
      for(int i=0;i<4;++i) o2[(quad*4+i)*NP + p] = make_float2(cR[i], cI[i]);
    }
  }
}

__global__ __launch_bounds__(256,3) void k_fusedall(const float* __restrict__ act,
    const short* __restrict__ A, float* __restrict__ out){
  __shared__ __align__(16) char smem[51200];
  const int bid = blockIdx.x;                             // 1024
  f32x4 cR={0.f,0.f,0.f,0.f}, cI={0.f,0.f,0.f,0.f};
  if(bid < 256){                                          // l=3, rows 56, NTIL 4
    const int b0 = bid*8;
    kf_pre<4>(act,smem,b0);
    const unsigned* Aw=(const unsigned*)(A+ABASE(3));
    kf_triple<2,1,3,0,4>(smem,Aw,cR,cI);
    kf_triple<2,2,3,1,4>(smem,Aw,cR,cI);
    kf_triple<3,0,3,2,4>(smem,Aw,cR,cI);
    kf_triple<3,1,3,3,4>(smem,Aw,cR,cI);
    kf_triple<3,2,3,4,4>(smem,Aw,cR,cI);
    kf_triple<3,3,3,5,4>(smem,Aw,cR,cI);
    kf_epi<3,4>(out,b0,cR,cI);
  } else if(bid < 512){                                   // l=2, rows 40, NTIL 3
    const int b0 = (bid-256)*8;
    kf_pre<3>(act,smem,b0);
    const unsigned* Aw=(const unsigned*)(A+ABASE(2));
    kf_triple<1,1,2,0,3>(smem,Aw,cR,cI);
    kf_triple<2,0,2,1,3>(smem,Aw,cR,cI);
    kf_triple<2,1,2,2,3>(smem,Aw,cR,cI);
    kf_triple<2,2,2,3,3>(smem,Aw,cR,cI);
    kf_triple<3,1,2,4,3>(smem,Aw,cR,cI);
    kf_triple<3,2,2,5,3>(smem,Aw,cR,cI);
    kf_triple<3,3,2,6,3>(smem,Aw,cR,cI);
    kf_epi<2,3>(out,b0,cR,cI);
  } else if(bid < 768){                                   // l=1, rows 24, NTIL 2
    const int b0 = (bid-512)*8;
    kf_pre<2>(act,smem,b0);
    const unsigned* Aw=(const unsigned*)(A+ABASE(1));
    kf_triple<1,0,1,0,2>(smem,Aw,cR,cI);
    kf_triple<1,1,1,1,2>(smem,Aw,cR,cI);
    kf_triple<2,1,1,2,2>(smem,Aw,cR,cI);
    kf_triple<2,2,1,3,2>(smem,Aw,cR,cI);
    kf_triple<3,2,1,4,2>(smem,Aw,cR,cI);
    kf_triple<3,3,1,5,2>(smem,Aw,cR,cI);
    kf_epi<1,2>(out,b0,cR,cI);
  } else {                                                // l=0, rows 8, NTIL 1
    const int b0 = (bid-768)*8;
    kf_pre<1>(act,smem,b0);
    const unsigned* Aw=(const unsigned*)(A+ABASE(0));
    kf_triple<0,0,0,0,1>(smem,Aw,cR,cI);
    kf_triple<1,1,0,1,1>(smem,Aw,cR,cI);
    kf_triple<2,2,0,2,1>(smem,Aw,cR,cI);
    kf_triple<3,3,0,3,1>(smem,Aw,cR,cI);
    kf_epi<0,1>(out,b0,cR,cI);
  }
}

// ================= host launch =================
extern "C" void kernel_launch(void* const* d_in, const int* in_sizes, int n_in,
                              void* d_out, int out_size, void* d_ws, size_t ws_size,
                              hipStream_t stream) {
  const float* act = (const float*)d_in[0];   // (2048,256,2) f32
  const float* W   = (const float*)d_in[1];   // (94208,2) f32
  const float* bn  = (const float*)d_in[2];   // (5888,) f32
  float* out = (float*)d_out;                 // (2048,256,2) f32

  short*  A    = (short*)((char*)d_ws + 24576);           // 754 KB bf16 A
  float2* part = (float2*)((char*)d_ws + 1048576);        // 1.5 MB partials

  hipLaunchKernelGGL(k_sumsq,   dim3(23*32), dim3(256), 0, stream, act, part);
  hipLaunchKernelGGL(k_buildA,  dim3(23),    dim3(256), 0, stream, W, bn, part, A);
  hipLaunchKernelGGL(k_fusedall,dim3(1024),  dim3(256), 0, stream, act, A, out);
}

// Round 6
// 143.043 us; speedup vs baseline: 2.4816x; 1.0118x over previous
//
#include <hip/hip_runtime.h>
#include <math.h>

typedef __attribute__((ext_vector_type(8))) short bf16x8;
typedef __attribute__((ext_vector_type(4))) float f32x4;

// ================= compile-time Clebsch-Gordan tables =================
constexpr double cfact(int n){ double r=1.0; for(int i=2;i<=n;++i) r*=(double)i; return r; }
constexpr double csqrt_(double x){ double g=(x>1.0)?x:1.0; for(int i=0;i<100;++i) g=0.5*(g+x/g); return g; }
constexpr double cg_coef_(int l1,int m1,int l2,int m2,int l,int m){
  double pre = csqrt_((double)(2*l+1)*cfact(l1+l2-l)*cfact(l1-l2+l)*cfact(-l1+l2+l)/cfact(l1+l2+l+1));
  pre = pre*csqrt_(cfact(l+m)*cfact(l-m)*cfact(l1-m1)*cfact(l1+m1)*cfact(l2-m2)*cfact(l2+m2));
  double s=0.0;
  for(int k=0;k<=l1+l2-l;++k){
    int d0=k,d1=l1+l2-l-k,d2=l1-m1-k,d3=l2+m2-k,d4=l-l2+m1+k,d5=l-l1-m2+k;
    if(d0<0||d1<0||d2<0||d3<0||d4<0||d5<0) continue;
    double den=cfact(d0)*cfact(d1)*cfact(d2)*cfact(d3)*cfact(d4)*cfact(d5);
    s+=((k&1)?-1.0:1.0)/den;
  }
  return pre*s;
}
struct CGList{ int n; float coef[64]; int mi[64]; int ni[64]; int pi[64]; };
constexpr CGList build_cg(int l1,int l2,int l){
  CGList T{};
  for(int i=0;i<2*l1+1;++i){
    for(int j=0;j<2*l2+1;++j){
      int m1=i-l1, m2=j-l2, m=m1+m2;
      if(m<-l||m>l) continue;
      double c=cg_coef_(l1,m1,l2,m2,l,m);
      if(c>1e-12||c<-1e-12){
        T.coef[T.n]=(float)c; T.mi[T.n]=i; T.ni[T.n]=j; T.pi[T.n]=m+l; T.n++;
      }
    }
  }
  return T;
}

// ================= layout constants =================
__device__ __host__ constexpr int AOFF(int l){ return l==0?0: l==1?16: l==2?64:144; }
__device__ __host__ constexpr int MLs(int l){ return l==0?1024: l==1?1536: l==2?1792:1536; }
__device__ __host__ constexpr int WOFF(int l){ return l==0?0: l==1?16384: l==2?40960:69632; }
__device__ __host__ constexpr int SOFF(int l){ return l==0?0: l==1?1024: l==2?2560:4352; }
__device__ __host__ constexpr int ABASE(int l){ return l==0?0: l==1?65536: l==2?163840:278528; }

#define DEVFN __device__ __forceinline__
#define BP 68    // btile row pitch in words
#define AP 68    // ldsA row pitch in words

DEVFN unsigned f2bf2(float x, float y){
  unsigned ux = __float_as_uint(x); ux = (ux + 0x7FFFu + ((ux>>16)&1u)) >> 16;
  unsigned uy = __float_as_uint(y); uy = (uy + 0x7FFFu + ((uy>>16)&1u)) >> 16;
  return (ux & 0xFFFFu) | (uy << 16);
}

template<int L1,int L2,int L>
DEVFN void cg_accum(const float2* F1, const float2* F2, float2* mid){
  constexpr CGList T = build_cg(L1,L2,L);
  #pragma unroll
  for(int e=0;e<T.n;++e){
    const float c = T.coef[e];
    const float2 a = F1[T.mi[e]];
    const float2 b = F2[T.ni[e]];
    float pr = a.x*b.x - a.y*b.y;
    float pim= a.x*b.y + a.y*b.x;
    mid[T.pi[e]].x += c*pr;
    mid[T.pi[e]].y += c*pim;
  }
}

// ===== K1: sumsq partials, GLOBAL-direct (no LDS, no barriers) + W-convert =====
template<int L1,int L2,int L>
DEVFN void k1g(const float2* __restrict__ act2, int b0, int u, int bh,
               float& ssa, float& ssb){
  constexpr int N1=2*L1+1, N2=2*L2+1, NP=2*L+1;
  const int t = u>>3, s0 = (u&7)*2;
  const float2* base1  = act2 + AOFF(L1) + t*N1;
  const float2* base2a = act2 + AOFF(L2) + s0*N2;
  const float2* base2b = base2a + N2;
  #pragma unroll 2
  for(int bi=0;bi<16;++bi){
    const size_t ro = (size_t)(b0 + bh*16 + bi)*256;
    float2 F1[N1], F2a[N2], F2b[N2], mida[NP], midb[NP];
    #pragma unroll
    for(int m=0;m<N1;++m) F1[m]=base1[ro+m];
    #pragma unroll
    for(int n=0;n<N2;++n){ F2a[n]=base2a[ro+n]; F2b[n]=base2b[ro+n]; }
    #pragma unroll
    for(int p=0;p<NP;++p){ mida[p]=make_float2(0.f,0.f); midb[p]=make_float2(0.f,0.f); }
    cg_accum<L1,L2,L>(F1,F2a,mida);
    cg_accum<L1,L2,L>(F1,F2b,midb);
    #pragma unroll
    for(int p=0;p<NP;++p){
      ssa += mida[p].x*mida[p].x + mida[p].y*mida[p].y;
      ssb += midb[p].x*midb[p].x + midb[p].y*midb[p].y;
    }
  }
}

DEVFN void convW(const float* __restrict__ W, short* __restrict__ A, int idx){
  int l = (idx<1024)?0 : (idx<2560)?1 : (idx<4352)?2 : 3;
  int c = idx - SOFF(l);
  int Ml = MLs(l);
  const float2* wbase = (const float2*)W + WOFF(l) + c;
  unsigned* Aw = (unsigned*)(A + ABASE(l));   // row pitch = Ml words
  #pragma unroll 4
  for(int o=0;o<16;++o){
    float2 w = wbase[(size_t)o*Ml];
    Aw[(size_t)o*Ml + c]      = f2bf2(w.x, -w.y);
    Aw[(size_t)(o+16)*Ml + c] = f2bf2(w.y,  w.x);
  }
}

__global__ __launch_bounds__(256) void k_sumsq(const float* __restrict__ act,
                                               float2* __restrict__ part,
                                               const float* __restrict__ W,
                                               short* __restrict__ A){
  const int bid = blockIdx.x;                // 1472 sumsq + 23 W-convert
  const int tid = threadIdx.x;
  if(bid >= 1472){                           // W -> bf16 A (no scale), hidden
    convW(W, A, (bid-1472)*256 + tid);
    return;
  }
  const int order[23] = {22,16,21,18,15,20,13,9,14,8,17,7,12,6,10,3,5,19,2,11,1,4,0};
  const int ti = order[bid>>6];
  const int chunk = bid&63;
  const int b0 = chunk*32;
  const int u = tid & 127, bh = tid >> 7;    // channels (2u,2u+1), batch half
  const float2* act2 = (const float2*)act;
  float ssa=0.f, ssb=0.f;
  switch(ti){
    case 0:  k1g<0,0,0>(act2,b0,u,bh,ssa,ssb); break;
    case 1:  k1g<1,1,0>(act2,b0,u,bh,ssa,ssb); break;
    case 2:  k1g<2,2,0>(act2,b0,u,bh,ssa,ssb); break;
    case 3:  k1g<3,3,0>(act2,b0,u,bh,ssa,ssb); break;
    case 4:  k1g<1,0,1>(act2,b0,u,bh,ssa,ssb); break;
    case 5:  k1g<1,1,1>(act2,b0,u,bh,ssa,ssb); break;
    case 6:  k1g<2,1,1>(act2,b0,u,bh,ssa,ssb); break;
    case 7:  k1g<2,2,1>(act2,b0,u,bh,ssa,ssb); break;
    case 8:  k1g<3,2,1>(act2,b0,u,bh,ssa,ssb); break;
    case 9:  k1g<3,3,1>(act2,b0,u,bh,ssa,ssb); break;
    case 10: k1g<1,1,2>(act2,b0,u,bh,ssa,ssb); break;
    case 11: k1g<2,0,2>(act2,b0,u,bh,ssa,ssb); break;
    case 12: k1g<2,1,2>(act2,b0,u,bh,ssa,ssb); break;
    case 13: k1g<2,2,2>(act2,b0,u,bh,ssa,ssb); break;
    case 14: k1g<3,1,2>(act2,b0,u,bh,ssa,ssb); break;
    case 15: k1g<3,2,2>(act2,b0,u,bh,ssa,ssb); break;
    case 16: k1g<3,3,2>(act2,b0,u,bh,ssa,ssb); break;
    case 17: k1g<2,1,3>(act2,b0,u,bh,ssa,ssb); break;
    case 18: k1g<2,2,3>(act2,b0,u,bh,ssa,ssb); break;
    case 19: k1g<3,0,3>(act2,b0,u,bh,ssa,ssb); break;
    case 20: k1g<3,1,3>(act2,b0,u,bh,ssa,ssb); break;
    case 21: k1g<3,2,3>(act2,b0,u,bh,ssa,ssb); break;
    default: k1g<3,3,3>(act2,b0,u,bh,ssa,ssb); break;
  }
  // coalesced partial store: row = ti*128 + chunk*2 + bh
  part[(size_t)((ti*64 + chunk)*2 + bh)*128 + u] = make_float2(ssa, ssb);
}

// ==== K2: tiny — reduce 128 partial rows per triple -> scale table s[5888] ====
__global__ __launch_bounds__(256) void k_scale(const float* __restrict__ bn,
                                               const float2* __restrict__ part,
                                               float* __restrict__ s){
  const int ti = blockIdx.x;                 // 23
  const int ch = threadIdx.x;                // 256 channels
  const int idx = ti*256 + ch;
  const int u = ch>>1;
  const float2* ps = part + (size_t)ti*128*128 + u;
  float sum = 0.f;
  #pragma unroll 8
  for(int r=0;r<128;++r){
    float2 v = ps[(size_t)r*128];
    sum += (ch&1) ? v.y : v.x;
  }
  int l = (idx<1024)?0 : (idx<2560)?1 : (idx<4352)?2 : 3;
  float divi = (l==0)?(1.f/2048.f) : (l==1)?(1.f/6144.f) : (l==2)?(1.f/10240.f) : (1.f/14336.f);
  float bstd = sqrtf(sum*divi);
  float nstd = 0.5f*(bn[idx]+bstd);
  s[idx] = 1.f/(nstd+1e-5f);
}

// ======== K3: fused recompute-GEMM (scale applied to mid in phase1) ========
// Block = 8 batches of one l. Per 64-word chunk (double-buffered ldsA):
//   { issue global loads for chunk cc+1;
//     phase1 CG recompute chunk cc (x s[ch]) -> btile (~600 cyc hides loads);
//     ds_write chunk cc+1 -> other ldsA buffer; barrier;
//     MFMA chunk cc (A from ldsA[cc&1], B from btile); barrier }
// Full-K register accumulation -> single float2 store per output element.

// LDS layout (bytes): [0,16384) sa | [16384,33792) btile | [33792,51200) ldsA x2
#define SA_B   0
#define BT_B   16384
#define LA_B   33792

template<int NTIL>
DEVFN void kf_pre(const float* __restrict__ act, char* smem, int b0){
  const int tid = threadIdx.x;
  const float2* actg2 = (const float2*)act + (size_t)b0*256;
  float4* s4 = (float4*)(smem + SA_B);
  const float4* ag = (const float4*)actg2;
  #pragma unroll
  for(int j=0;j<4;++j) s4[j*256+tid] = ag[j*256+tid];
  unsigned* btile = (unsigned*)(smem + BT_B);
  for(int i=tid; i<NTIL*16*BP; i+=256) btile[i]=0;
  __syncthreads();
}

template<int L1,int L2,int L,int Q,int NTIL>
DEVFN void kf_triple(char* smem, const unsigned* __restrict__ Aw,
                     const float* __restrict__ sg, f32x4& cR, f32x4& cI){
  constexpr int N1=2*L1+1, N2=2*L2+1, NP=2*L+1;
  constexpr int Ml = MLs(L);
  const float2* sa = (const float2*)(smem + SA_B);
  unsigned* btile  = (unsigned*)(smem + BT_B);
  unsigned* ldsA   = (unsigned*)(smem + LA_B);
  const int tid = threadIdx.x;
  const int lane = tid & 63, w = tid >> 6;
  const int col = lane & 15, quad = lane >> 4;
  const int up = tid & 31, bi = tid >> 5;    // channel-pair-in-chunk, batch
  const int r0 = tid>>4,       j0 = (tid&15)*4;
  const int r1 = (tid+256)>>4;
  // prologue: stage chunk 0 into buffer 0
  {
    const int base = (Q*4)*64;
    uint4 v0 = *(const uint4*)(Aw + (size_t)r0*Ml + base + j0);
    uint4 v1 = *(const uint4*)(Aw + (size_t)r1*Ml + base + j0);
    *(uint4*)(ldsA + r0*AP + j0) = v0;
    *(uint4*)(ldsA + r1*AP + j0) = v1;
  }
  #pragma unroll 1
  for(int cc=0; cc<4; ++cc){
    unsigned* cbuf = ldsA + (cc&1)*(32*AP);
    unsigned* nbuf = ldsA + ((cc+1)&1)*(32*AP);
    // ---- issue next A-chunk loads (completion hidden under phase1) ----
    uint4 v0, v1;
    if(cc<3){
      const int base = (Q*4+cc+1)*64;
      v0 = *(const uint4*)(Aw + (size_t)r0*Ml + base + j0);
      v1 = *(const uint4*)(Aw + (size_t)r1*Ml + base + j0);
    }
    // ---- phase1: CG recompute (scaled) for 64 K-words x 8 batches ----
    {
      const float2 s2 = *(const float2*)(sg + SOFF(L) + Q*256 + cc*64 + 2*up);
      const int u = cc*32 + up;              // channel pair (2u,2u+1)
      const int t = u>>3, s0 = (u&7)*2;
      const float2* arow = sa + bi*256;
      float2 F1[N1], F2a[N2], F2b[N2], mida[NP], midb[NP];
      #pragma unroll
      for(int m=0;m<N1;++m) F1[m]=arow[AOFF(L1)+t*N1+m];
      #pragma unroll
      for(int n=0;n<N2;++n){
        F2a[n]=arow[AOFF(L2)+s0*N2+n];
        F2b[n]=arow[AOFF(L2)+(s0+1)*N2+n];
      }
      #pragma unroll
      for(int p=0;p<NP;++p){ mida[p]=make_float2(0.f,0.f); midb[p]=make_float2(0.f,0.f); }
      cg_accum<L1,L2,L>(F1,F2a,mida);
      cg_accum<L1,L2,L>(F1,F2b,midb);
      #pragma unroll
      for(int p=0;p<NP;++p){
        uint2 v;
        v.x = f2bf2(mida[p].x*s2.x, mida[p].y*s2.x);
        v.y = f2bf2(midb[p].x*s2.y, midb[p].y*s2.y);
        *(uint2*)(btile + (size_t)(bi*NP+p)*BP + 2*up) = v;
      }
    }
    // ---- land next A-chunk into the buffer MFMA won't read this chunk ----
    if(cc<3){
      *(uint4*)(nbuf + r0*AP + j0) = v0;
      *(uint4*)(nbuf + r1*AP + j0) = v1;
    }
    __syncthreads();
    // ---- MFMA accumulate (A and B both from LDS) ----
    if(w < NTIL){
      const unsigned* ar0 = cbuf + col*AP + quad*4;
      const unsigned* ar1 = cbuf + (col+16)*AP + quad*4;
      const unsigned* bb  = btile + (w*16+col)*BP + quad*4;
      #pragma unroll
      for(int ks=0; ks<4; ++ks){
        bf16x8 b  = *(const bf16x8*)(bb + ks*16);
        bf16x8 A0 = *(const bf16x8*)(ar0 + ks*16);
        bf16x8 A1 = *(const bf16x8*)(ar1 + ks*16);
        cR = __builtin_amdgcn_mfma_f32_16x16x32_bf16(A0, b, cR, 0, 0, 0);
        cI = __builtin_amdgcn_mfma_f32_16x16x32_bf16(A1, b, cI, 0, 0, 0);
      }
    }
    __syncthreads();
  }
}

template<int L,int NTIL>
DEVFN void kf_epi(float* __restrict__ out, int b0, f32x4 cR, f32x4 cI){
  constexpr int NP = 2*L+1;
  const int tid = threadIdx.x, lane = tid & 63, w = tid >> 6;
  const int col = lane & 15, quad = lane >> 4;
  if(w < NTIL){
    const int r = w*16 + col;
    if(r < 8*NP){
      const int b = b0 + r/NP, p = r - (r/NP)*NP;
      float2* o2 = (float2*)out + (size_t)b*256 + AOFF(L);
      #pragma unroll
      for(int i=0;i<4;++i) o2[(quad*4+i)*NP + p] = make_float2(cR[i], cI[i]);
    }
  }
}

__global__ __launch_bounds__(256,3) void k_fusedall(const float* __restrict__ act,
    const short* __restrict__ A, const float* __restrict__ sg,
    float* __restrict__ out){
  __shared__ __align__(16) char smem[51200];
  const int bid = blockIdx.x;                             // 1024
  f32x4 cR={0.f,0.f,0.f,0.f}, cI={0.f,0.f,0.f,0.f};
  if(bid < 256){                                          // l=3, rows 56, NTIL 4
    const int b0 = bid*8;
    kf_pre<4>(act,smem,b0);
    const unsigned* Aw=(const unsigned*)(A+ABASE(3));
    kf_triple<2,1,3,0,4>(smem,Aw,sg,cR,cI);
    kf_triple<2,2,3,1,4>(smem,Aw,sg,cR,cI);
    kf_triple<3,0,3,2,4>(smem,Aw,sg,cR,cI);
    kf_triple<3,1,3,3,4>(smem,Aw,sg,cR,cI);
    kf_triple<3,2,3,4,4>(smem,Aw,sg,cR,cI);
    kf_triple<3,3,3,5,4>(smem,Aw,sg,cR,cI);
    kf_epi<3,4>(out,b0,cR,cI);
  } else if(bid < 512){                                   // l=2, rows 40, NTIL 3
    const int b0 = (bid-256)*8;
    kf_pre<3>(act,smem,b0);
    const unsigned* Aw=(const unsigned*)(A+ABASE(2));
    kf_triple<1,1,2,0,3>(smem,Aw,sg,cR,cI);
    kf_triple<2,0,2,1,3>(smem,Aw,sg,cR,cI);
    kf_triple<2,1,2,2,3>(smem,Aw,sg,cR,cI);
    kf_triple<2,2,2,3,3>(smem,Aw,sg,cR,cI);
    kf_triple<3,1,2,4,3>(smem,Aw,sg,cR,cI);
    kf_triple<3,2,2,5,3>(smem,Aw,sg,cR,cI);
    kf_triple<3,3,2,6,3>(smem,Aw,sg,cR,cI);
    kf_epi<2,3>(out,b0,cR,cI);
  } else if(bid < 768){                                   // l=1, rows 24, NTIL 2
    const int b0 = (bid-512)*8;
    kf_pre<2>(act,smem,b0);
    const unsigned* Aw=(const unsigned*)(A+ABASE(1));
    kf_triple<1,0,1,0,2>(smem,Aw,sg,cR,cI);
    kf_triple<1,1,1,1,2>(smem,Aw,sg,cR,cI);
    kf_triple<2,1,1,2,2>(smem,Aw,sg,cR,cI);
    kf_triple<2,2,1,3,2>(smem,Aw,sg,cR,cI);
    kf_triple<3,2,1,4,2>(smem,Aw,sg,cR,cI);
    kf_triple<3,3,1,5,2>(smem,Aw,sg,cR,cI);
    kf_epi<1,2>(out,b0,cR,cI);
  } else {                                                // l=0, rows 8, NTIL 1
    const int b0 = (bid-768)*8;
    kf_pre<1>(act,smem,b0);
    const unsigned* Aw=(const unsigned*)(A+ABASE(0));
    kf_triple<0,0,0,0,1>(smem,Aw,sg,cR,cI);
    kf_triple<1,1,0,1,1>(smem,Aw,sg,cR,cI);
    kf_triple<2,2,0,2,1>(smem,Aw,sg,cR,cI);
    kf_triple<3,3,0,3,1>(smem,Aw,sg,cR,cI);
    kf_epi<0,1>(out,b0,cR,cI);
  }
}

// ================= host launch =================
extern "C" void kernel_launch(void* const* d_in, const int* in_sizes, int n_in,
                              void* d_out, int out_size, void* d_ws, size_t ws_size,
                              hipStream_t stream) {
  const float* act = (const float*)d_in[0];   // (2048,256,2) f32
  const float* W   = (const float*)d_in[1];   // (94208,2) f32
  const float* bn  = (const float*)d_in[2];   // (5888,) f32
  float* out = (float*)d_out;                 // (2048,256,2) f32

  float*  s    = (float*)d_ws;                            // 5888 f32 scale table
  short*  A    = (short*)((char*)d_ws + 24576);           // 754 KB bf16 A (unscaled)
  float2* part = (float2*)((char*)d_ws + 1048576);        // 3 MB partials

  hipLaunchKernelGGL(k_sumsq,   dim3(1495), dim3(256), 0, stream, act, part, W, A);
  hipLaunchKernelGGL(k_scale,   dim3(23),   dim3(256), 0, stream, bn, part, s);
  hipLaunchKernelGGL(k_fusedall,dim3(1024), dim3(256), 0, stream, act, A, s, out);
}